// Round 1
// baseline (2143.147 us; speedup 1.0000x reference)
//
#include <hip/hip_runtime.h>
#include <math.h>

// Problem constants
#define T_FRAMES 16384
#define P_SEG    64
#define S_N      128
#define A_N      16
#define VD       1024
#define VO       256
#define TD       768
#define TO       256
#define HH       512
#define NTXT     2113            // 64 para + 1 question + 2048 a_texts
#define NCAND    32528           // 16 + 127*256 candidate (k, ci, a) rows
#define NASC     2049            // state0 + 2048 inputs_pre rows

// ---------------------------------------------------------------------------
// Generic fp32 tiled GEMM: C = op(A @ B + bias)
//   A: (M,K) row-major.  B: (K,N) row-major if !BT, else (N,K) row-major (A@B^T).
//   128x128 tile, BK=16, 256 threads, 8x8 per-thread accumulators.
// ---------------------------------------------------------------------------
template<bool BT, bool RELU>
__global__ __launch_bounds__(256) void sgemm(const float* __restrict__ A,
                                             const float* __restrict__ B,
                                             const float* __restrict__ bias,
                                             float* __restrict__ C,
                                             int M, int N, int K)
{
    __shared__ float As[16][132];   // [k][m], padded to avoid bank conflicts
    __shared__ float Bs[16][132];   // [k][n]

    const int tid = threadIdx.x;
    const int tx = tid & 15;        // 0..15 -> n groups
    const int ty = tid >> 4;        // 0..15 -> m groups
    const int bm = blockIdx.y * 128;
    const int bn = blockIdx.x * 128;

    float acc[8][8];
#pragma unroll
    for (int i = 0; i < 8; ++i)
#pragma unroll
        for (int j = 0; j < 8; ++j) acc[i][j] = 0.f;

    for (int k0 = 0; k0 < K; k0 += 16) {
        // --- stage A tile (128 rows x 16 k) : 2 float4 per thread ---
#pragma unroll
        for (int p = 0; p < 2; ++p) {
            int f   = tid + p * 256;       // 0..511
            int row = f >> 2;              // 0..127
            int kq  = (f & 3) << 2;        // 0,4,8,12
            float4 v = make_float4(0.f, 0.f, 0.f, 0.f);
            int gr = bm + row;
            if (gr < M) v = *(const float4*)(A + (size_t)gr * K + k0 + kq);
            As[kq + 0][row] = v.x; As[kq + 1][row] = v.y;
            As[kq + 2][row] = v.z; As[kq + 3][row] = v.w;
        }
        // --- stage B tile ---
        if (!BT) {
#pragma unroll
            for (int p = 0; p < 2; ++p) {
                int f  = tid + p * 256;
                int kr = f >> 5;            // 0..15
                int nc = (f & 31) << 2;     // 0..124
                float4 v = make_float4(0.f, 0.f, 0.f, 0.f);
                int gn = bn + nc;
                if (gn < N) v = *(const float4*)(B + (size_t)(k0 + kr) * N + gn);
                *(float4*)&Bs[kr][nc] = v;
            }
        } else {
#pragma unroll
            for (int p = 0; p < 2; ++p) {
                int f  = tid + p * 256;
                int n  = f >> 2;            // 0..127
                int kq = (f & 3) << 2;
                float4 v = make_float4(0.f, 0.f, 0.f, 0.f);
                int gn = bn + n;
                if (gn < N) v = *(const float4*)(B + (size_t)gn * K + k0 + kq);
                Bs[kq + 0][n] = v.x; Bs[kq + 1][n] = v.y;
                Bs[kq + 2][n] = v.z; Bs[kq + 3][n] = v.w;
            }
        }
        __syncthreads();

#pragma unroll
        for (int k = 0; k < 16; ++k) {
            float4 a0 = *(float4*)&As[k][ty * 4];
            float4 a1 = *(float4*)&As[k][64 + ty * 4];
            float4 b0 = *(float4*)&Bs[k][tx * 4];
            float4 b1 = *(float4*)&Bs[k][64 + tx * 4];
            float am[8] = {a0.x, a0.y, a0.z, a0.w, a1.x, a1.y, a1.z, a1.w};
            float bb[8] = {b0.x, b0.y, b0.z, b0.w, b1.x, b1.y, b1.z, b1.w};
#pragma unroll
            for (int i = 0; i < 8; ++i)
#pragma unroll
                for (int j = 0; j < 8; ++j)
                    acc[i][j] = fmaf(am[i], bb[j], acc[i][j]);
        }
        __syncthreads();
    }

    // epilogue
#pragma unroll
    for (int i = 0; i < 8; ++i) {
        int gm = bm + (i >> 2) * 64 + ty * 4 + (i & 3);
        if (gm >= M) continue;
#pragma unroll
        for (int j = 0; j < 8; ++j) {
            int gn = bn + (j >> 2) * 64 + tx * 4 + (j & 3);
            if (gn >= N) continue;
            float v = acc[i][j] + bias[gn];
            if (RELU) v = fmaxf(v, 0.f);
            C[(size_t)gm * N + gn] = v;
        }
    }
}

// ---------------------------------------------------------------------------
// softmax over 64 paragraph scores (1 wave)
// ---------------------------------------------------------------------------
__global__ void score_softmax(const float* __restrict__ ps, float* __restrict__ sc)
{
    int lane = threadIdx.x;
    float x = ps[lane];
    float m = x;
    for (int off = 32; off; off >>= 1) m = fmaxf(m, __shfl_xor(m, off));
    float e = expf(x - m);
    float s = e;
    for (int off = 32; off; off >>= 1) s += __shfl_xor(s, off);
    sc[lane] = e / s;
}

// w_t = sum_p [s_p <= t < e_p] * score_p / len_p
__global__ __launch_bounds__(256) void wt_kernel(const int* __restrict__ ts,
                                                 const float* __restrict__ sc,
                                                 float* __restrict__ wt)
{
    __shared__ int ss[64], se[64];
    __shared__ float sw[64];
    int tid = threadIdx.x;
    if (tid < 64) {
        int s = ts[2 * tid];
        int e = ts[2 * tid + 1];
        if (e < s + 1) e = s + 1;
        ss[tid] = s; se[tid] = e;
        sw[tid] = sc[tid] / (float)(e - s);
    }
    __syncthreads();
    int t = blockIdx.x * 256 + tid;
    if (t < T_FRAMES) {
        float w = 0.f;
#pragma unroll
        for (int p = 0; p < 64; ++p)
            if (t >= ss[p] && t < se[p]) w += sw[p];
        wt[t] = w;
    }
}

// partial weighted reduction of H1 rows (video part): upart[b][col] over 128-row chunk
__global__ __launch_bounds__(256) void upart_kernel(const float* __restrict__ H1,
                                                    const float* __restrict__ wt,
                                                    float* __restrict__ upart)
{
    int tid = threadIdx.x;
    int t0 = blockIdx.x * 128;
    float acc[4] = {0.f, 0.f, 0.f, 0.f};
    for (int t = 0; t < 128; ++t) {
        float w = wt[t0 + t];
        const float* row = H1 + (size_t)(t0 + t) * VD;
#pragma unroll
        for (int c = 0; c < 4; ++c)
            acc[c] = fmaf(w, row[tid + c * 256], acc[c]);
    }
#pragma unroll
    for (int c = 0; c < 4; ++c)
        upart[(size_t)blockIdx.x * VD + tid + c * 256] = acc[c];
}

__global__ __launch_bounds__(256) void ureduce2(const float* __restrict__ upart,
                                                float* __restrict__ u)
{
    int col = blockIdx.x * 256 + threadIdx.x;   // 1024 cols
    float acc = 0.f;
    for (int b = 0; b < 128; ++b) acc += upart[(size_t)b * VD + col];
    u[col] = acc;
}

// video_seg = u @ wv2 + bv2   (256 outputs)
__global__ __launch_bounds__(256) void videoseg_kernel(const float* __restrict__ u,
                                                       const float* __restrict__ wv2,
                                                       const float* __restrict__ bv2,
                                                       float* __restrict__ vseg)
{
    int j = threadIdx.x;
    float acc = bv2[j];
    for (int i = 0; i < VD; ++i) acc = fmaf(u[i], wv2[(size_t)i * VO + j], acc);
    vseg[j] = acc;
}

// text_seg = score @ T2[0:64]
__global__ __launch_bounds__(256) void textseg_kernel(const float* __restrict__ sc,
                                                      const float* __restrict__ T2,
                                                      float* __restrict__ tseg)
{
    int j = threadIdx.x;
    float acc = 0.f;
    for (int p = 0; p < 64; ++p) acc = fmaf(sc[p], T2[(size_t)p * TO + j], acc);
    tseg[j] = acc;
}

// stack [para; question; a_texts] into Xt (2113 x 768)
__global__ __launch_bounds__(256) void copy_xt(const float* __restrict__ para,
                                               const float* __restrict__ question,
                                               const float* __restrict__ atexts,
                                               float* __restrict__ Xt)
{
    size_t total = (size_t)NTXT * TD;
    for (size_t id = (size_t)blockIdx.x * 256 + threadIdx.x; id < total;
         id += (size_t)gridDim.x * 256) {
        int r = (int)(id / TD);
        int c = (int)(id - (size_t)r * TD);
        float v;
        if (r < 64)       v = para[(size_t)r * TD + c];
        else if (r == 64) v = question[c];
        else              v = atexts[(size_t)(r - 65) * TD + c];
        Xt[id] = v;
    }
}

// Xp row r = [video_seg | text_seg | q + T2[65+r] | btn[r]]
__global__ __launch_bounds__(256) void xp_build(const float* __restrict__ vseg,
                                                const float* __restrict__ tseg,
                                                const float* __restrict__ T2,
                                                const float* __restrict__ btn,
                                                float* __restrict__ Xp)
{
    size_t total = (size_t)2048 * 1024;
    for (size_t id = (size_t)blockIdx.x * 256 + threadIdx.x; id < total;
         id += (size_t)gridDim.x * 256) {
        int r = (int)(id >> 10);
        int c = (int)(id & 1023);
        float v;
        if (c < 256)      v = vseg[c];
        else if (c < 512) v = tseg[c - 256];
        else if (c < 768) v = T2[(size_t)64 * TO + (c - 512)] +
                              T2[(size_t)(65 + r) * TO + (c - 512)];
        else              v = btn[(size_t)r * VO + (c - 768)];
        Xp[id] = v;
    }
}

// ASC = [state0 ; inputs_pre]  (2049 x 512)
__global__ __launch_bounds__(256) void asc_build(const float* __restrict__ state0,
                                                 const float* __restrict__ IP,
                                                 float* __restrict__ ASC)
{
    size_t total = (size_t)NASC * HH;
    for (size_t id = (size_t)blockIdx.x * 256 + threadIdx.x; id < total;
         id += (size_t)gridDim.x * 256) {
        int r = (int)(id >> 9);
        int c = (int)(id & 511);
        ASC[id] = (r == 0) ? state0[c] : IP[(size_t)(r - 1) * HH + c];
    }
}

__device__ __forceinline__ float sigm(float x) { return 1.f / (1.f + expf(-x)); }

// GRU gates -> h_new for every (k, cand, action) row
__global__ __launch_bounds__(256) void hn_build(const float* __restrict__ GI,
                                                const float* __restrict__ GH,
                                                const float* __restrict__ ASC,
                                                float* __restrict__ HN)
{
    size_t total = (size_t)NCAND * HH;
    for (size_t id = (size_t)blockIdx.x * 256 + threadIdx.x; id < total;
         id += (size_t)gridDim.x * 256) {
        int r = (int)(id >> 9);
        int c = (int)(id & 511);
        int crow, girow;
        if (r < 16) { crow = 0; girow = r; }
        else {
            int rr = r - 16;
            int k  = 1 + (rr >> 8);
            int rem = rr & 255;
            int ci = rem >> 4;
            int a  = rem & 15;
            crow = 1 + (k - 1) * 16 + ci;
            girow = k * 16 + a;
        }
        const float* gi = GI + (size_t)girow * (3 * HH);
        const float* gh = GH + (size_t)crow * (3 * HH);
        float ir = gi[c], iz = gi[512 + c], inn = gi[1024 + c];
        float hr = gh[c], hz = gh[512 + c], hn = gh[1024 + c];
        float h  = ASC[(size_t)crow * HH + c];
        float rg = sigm(ir + hr);
        float z  = sigm(iz + hz);
        float n  = tanhf(inn + rg * hn);
        HN[id] = (1.f - z) * n + z * h;
    }
}

// LG[r] = dot(L1[r], wj2) + bj2   (wave per row)
__global__ __launch_bounds__(256) void lg_kernel(const float* __restrict__ L1,
                                                 const float* __restrict__ wj2,
                                                 const float* __restrict__ bj2,
                                                 float* __restrict__ LG)
{
    __shared__ float w[512];
    int tid = threadIdx.x;
    w[tid] = wj2[tid];
    w[tid + 256] = wj2[tid + 256];
    __syncthreads();
    int wave = tid >> 6, lane = tid & 63;
    float b = bj2[0];
    for (int r = blockIdx.x * 4 + wave; r < NCAND; r += gridDim.x * 4) {
        const float* row = L1 + (size_t)r * HH;
        float acc = 0.f;
#pragma unroll
        for (int q = 0; q < 8; ++q)
            acc = fmaf(row[lane + q * 64], w[lane + q * 64], acc);
        for (int off = 32; off; off >>= 1) acc += __shfl_xor(acc, off);
        if (lane == 0) LG[r] = acc + b;
    }
}

// sequential pointer-chase through the precomputed logits table (1 wave)
__global__ void chase_kernel(const float* __restrict__ LG, float* __restrict__ out)
{
    int lane = threadIdx.x;      // 64 threads
    int base = 0;                // k=0 rows 0..15 (candidate = state0)
    for (int k = 0; k < S_N; ++k) {
        float v = -INFINITY;
        if (lane < 16) {
            v = LG[base + lane];
            out[k * 16 + lane] = v;
        }
        int bi = lane;
        // argmax over lanes 0..15 with first-max (lowest index) tie-break
        for (int off = 8; off >= 1; off >>= 1) {
            float ov = __shfl_xor(v, off);
            int   oi = __shfl_xor(bi, off);
            if (ov > v || (ov == v && oi < bi)) { v = ov; bi = oi; }
        }
        int ci = __shfl(bi, 0);
        base = 16 + k * 256 + ci * 16;   // rows for step k+1, candidate ci
    }
}

// ---------------------------------------------------------------------------
extern "C" void kernel_launch(void* const* d_in, const int* in_sizes, int n_in,
                              void* d_out, int out_size, void* d_ws, size_t ws_size,
                              hipStream_t stream)
{
    const float* video      = (const float*)d_in[0];
    const float* para       = (const float*)d_in[1];
    const float* question   = (const float*)d_in[2];
    const float* paras_scr  = (const float*)d_in[3];
    const float* a_texts    = (const float*)d_in[4];
    const float* a_buttons  = (const float*)d_in[5];
    const int*   timestamps = (const int*)d_in[6];
    const float* wv1 = (const float*)d_in[7];
    const float* bv1 = (const float*)d_in[8];
    const float* wv2 = (const float*)d_in[9];
    const float* bv2 = (const float*)d_in[10];
    const float* wt1 = (const float*)d_in[11];
    const float* bt1 = (const float*)d_in[12];
    const float* wt2 = (const float*)d_in[13];
    const float* bt2 = (const float*)d_in[14];
    const float* wp1 = (const float*)d_in[15];
    const float* bp1 = (const float*)d_in[16];
    const float* wp2 = (const float*)d_in[17];
    const float* bp2 = (const float*)d_in[18];
    const float* w_ih = (const float*)d_in[19];
    const float* b_ih = (const float*)d_in[20];
    const float* w_hh = (const float*)d_in[21];
    const float* b_hh = (const float*)d_in[22];
    const float* wj1 = (const float*)d_in[23];
    const float* bj1 = (const float*)d_in[24];
    const float* wj2 = (const float*)d_in[25];
    const float* bj2 = (const float*)d_in[26];
    const float* state0 = (const float*)d_in[27];

    float* ws = (float*)d_ws;
    size_t off = 0;
    auto alloc = [&](size_t n) { size_t o = off; off += (n + 63) & ~(size_t)63; return o; };

    float* sc    = ws + alloc(64);
    float* wt    = ws + alloc(T_FRAMES);
    float* u     = ws + alloc(VD);
    float* upart = ws + alloc((size_t)128 * VD);
    float* vseg  = ws + alloc(VO);
    float* tseg  = ws + alloc(TO);
    float* H1    = ws + alloc((size_t)18432 * VD);   // video(16384)+buttons(2048) hidden; reused as L1
    float* Xt    = ws + alloc((size_t)NTXT * TD);
    float* T1    = ws + alloc((size_t)NTXT * TD);
    float* T2m   = ws + alloc((size_t)NTXT * TO);
    float* btn   = ws + alloc((size_t)2048 * VO);
    float* Xp    = ws + alloc((size_t)2048 * 1024);
    float* P1    = ws + alloc((size_t)2048 * 1024);
    float* IP    = ws + alloc((size_t)2048 * HH);
    float* GI    = ws + alloc((size_t)2048 * 3 * HH);
    float* ASC   = ws + alloc((size_t)NASC * HH);
    float* GH    = ws + alloc((size_t)NASC * 3 * HH);
    float* HN    = ws + alloc((size_t)NCAND * HH);
    float* LG    = ws + alloc(NCAND);
    float* L1    = H1;  // reuse: H1 dead after btn GEMM + u reduction

    // 1. paragraph softmax
    score_softmax<<<1, 64, 0, stream>>>(paras_scr, sc);
    // 2. per-frame weights
    wt_kernel<<<T_FRAMES / 256, 256, 0, stream>>>(timestamps, sc, wt);
    // 3. video layer-1: H1[0:16384] = relu(video@wv1+bv1)
    sgemm<false, true><<<dim3(VD / 128, T_FRAMES / 128), 256, 0, stream>>>(
        video, wv1, bv1, H1, T_FRAMES, VD, VD);
    // 4. buttons layer-1: H1[16384:18432] = relu(a_buttons@wv1+bv1)
    sgemm<false, true><<<dim3(VD / 128, 2048 / 128), 256, 0, stream>>>(
        a_buttons, wv1, bv1, H1 + (size_t)T_FRAMES * VD, 2048, VD, VD);
    // 5-6. weighted reduce of video hidden rows -> u
    upart_kernel<<<128, 256, 0, stream>>>(H1, wt, upart);
    ureduce2<<<VD / 256, 256, 0, stream>>>(upart, u);
    // 7. video_seg = u@wv2+bv2
    videoseg_kernel<<<1, 256, 0, stream>>>(u, wv2, bv2, vseg);
    // 8. btn = H1[16384:]@wv2+bv2
    sgemm<false, false><<<dim3(VO / 128, 2048 / 128), 256, 0, stream>>>(
        H1 + (size_t)T_FRAMES * VD, wv2, bv2, btn, 2048, VO, VD);
    // 9. stack text rows
    copy_xt<<<2048, 256, 0, stream>>>(para, question, a_texts, Xt);
    // 10-11. text MLP
    sgemm<false, true><<<dim3(TD / 128, (NTXT + 127) / 128), 256, 0, stream>>>(
        Xt, wt1, bt1, T1, NTXT, TD, TD);
    sgemm<false, false><<<dim3(TO / 128, (NTXT + 127) / 128), 256, 0, stream>>>(
        T1, wt2, bt2, T2m, NTXT, TO, TD);
    // 12. text_seg
    textseg_kernel<<<1, 256, 0, stream>>>(sc, T2m, tseg);
    // 13. concat input
    xp_build<<<2048, 256, 0, stream>>>(vseg, tseg, T2m, btn, Xp);
    // 14-15. pre-GRU MLP -> inputs_pre
    sgemm<false, true><<<dim3(1024 / 128, 2048 / 128), 256, 0, stream>>>(
        Xp, wp1, bp1, P1, 2048, 1024, 1024);
    sgemm<false, false><<<dim3(HH / 128, 2048 / 128), 256, 0, stream>>>(
        P1, wp2, bp2, IP, 2048, HH, 1024);
    // 16. candidate state stack
    asc_build<<<1024, 256, 0, stream>>>(state0, IP, ASC);
    // 17. gi for all (k,a):  IP @ w_ih^T + b_ih
    sgemm<true, false><<<dim3(1536 / 128, 2048 / 128), 256, 0, stream>>>(
        IP, w_ih, b_ih, GI, 2048, 3 * HH, HH);
    // 18. gh for all candidate states: ASC @ w_hh^T + b_hh
    sgemm<true, false><<<dim3(1536 / 128, (NASC + 127) / 128), 256, 0, stream>>>(
        ASC, w_hh, b_hh, GH, NASC, 3 * HH, HH);
    // 19. GRU gate fusion -> h_new for all candidate rows
    hn_build<<<4096, 256, 0, stream>>>(GI, GH, ASC, HN);
    // 20. judge layer 1: L1 = relu(HN@wj1+bj1)
    sgemm<false, true><<<dim3(HH / 128, (NCAND + 127) / 128), 256, 0, stream>>>(
        HN, wj1, bj1, L1, NCAND, HH, HH);
    // 21. logits
    lg_kernel<<<512, 256, 0, stream>>>(L1, wj2, bj2, LG);
    // 22. sequential path chase + output
    chase_kernel<<<1, 64, 0, stream>>>(LG, (float*)d_out);
}

// Round 2
// 909.479 us; speedup vs baseline: 2.3565x; 2.3565x over previous
//
#include <hip/hip_runtime.h>
#include <math.h>

#define T_FRAMES 16384
#define S_N      128
#define VD       1024
#define VO       256
#define TD       768
#define TO       256
#define HH       512
#define NTXT     2113            // 64 para + 1 question + 2048 a_texts
#define NCAND    32528           // 16 + 127*256 candidate (k, ci, a) rows
#define NASC     2049            // state0 + 2048 inputs_pre rows

typedef __attribute__((ext_vector_type(8))) short s8v;    // 8 x bf16 bits
typedef __attribute__((ext_vector_type(4))) short s4v;
typedef __attribute__((ext_vector_type(4))) float f32x4;

__device__ __forceinline__ float bf2f(short h) {
    return __builtin_bit_cast(float, ((unsigned)(unsigned short)h) << 16);
}
// round-to-nearest-even split (used for weights, once per launch)
__device__ __forceinline__ void split_rn(float v, short& h, short& l) {
    unsigned u = __builtin_bit_cast(unsigned, v);
    unsigned short uh = (unsigned short)((u + 0x7fff + ((u >> 16) & 1)) >> 16);
    float hf = bf2f((short)uh);
    float lf = v - hf;
    unsigned ul = __builtin_bit_cast(unsigned, lf);
    unsigned short us = (unsigned short)((ul + 0x7fff + ((ul >> 16) & 1)) >> 16);
    h = (short)uh; l = (short)us;
}
// fast truncation split (used on activations in the GEMM staging hot path)
__device__ __forceinline__ void split_tr(float v, short& h, short& l) {
    unsigned u = __builtin_bit_cast(unsigned, v);
    unsigned short uh = (unsigned short)(u >> 16);
    float lf = v - bf2f((short)uh);
    h = (short)uh;
    l = (short)(__builtin_bit_cast(unsigned, lf) >> 16);
}

// ---------------------------------------------------------------------------
// bf16-split MFMA GEMM: C = op(A @ B + bias)
//  A: (M,K) fp32 row-major, split on the fly. Rows >= A2from come from A2.
//  B: pre-split bf16 hi/lo in B-TRANSPOSED layout (N,K) row-major.
//  128x128 tile, BK=32, 256 threads (4 waves, 2x2), 4x4 16x16x32 frags/wave.
// ---------------------------------------------------------------------------
template<bool RELU>
__global__ __launch_bounds__(256, 2) void mgemm(
    const float* __restrict__ A, const float* __restrict__ A2, int A2from,
    const short* __restrict__ Bh, const short* __restrict__ Bl,
    const float* __restrict__ bias, float* __restrict__ C,
    int M, int N, int K)
{
    __shared__ short As_h[128][40];   // 32 k padded to 40 (80B rows, 16B-aligned)
    __shared__ short As_l[128][40];
    __shared__ short Bs_h[128][40];   // B^T tile: [n][k]
    __shared__ short Bs_l[128][40];

    const int tid  = threadIdx.x;
    const int lane = tid & 63;
    const int wv   = tid >> 6;
    const int wr   = wv >> 1, wc = wv & 1;
    const int fr   = lane & 15;       // fragment row/col index
    const int fg   = lane >> 4;       // k-group
    const int bm   = blockIdx.y * 128;
    const int bn   = blockIdx.x * 128;

    const int srow = tid >> 1;            // staging row 0..127
    const int skq  = (tid & 1) * 16;      // staging k offset 0 / 16

    f32x4 acc[4][4];
#pragma unroll
    for (int m = 0; m < 4; ++m)
#pragma unroll
        for (int n = 0; n < 4; ++n) acc[m][n] = (f32x4){0.f, 0.f, 0.f, 0.f};

    for (int k0 = 0; k0 < K; k0 += 32) {
        // ---- stage A (fp32 -> split bf16) ----
        {
            s8v h0 = 0, h1 = 0, l0 = 0, l1 = 0;
            int gr = bm + srow;
            if (gr < M) {
                const float* src = (gr < A2from) ? (A + (size_t)gr * K)
                                                 : (A2 + (size_t)(gr - A2from) * K);
                const float4* p = (const float4*)(src + k0 + skq);
#pragma unroll
                for (int q = 0; q < 4; ++q) {
                    float4 v = p[q];
                    float vv[4] = {v.x, v.y, v.z, v.w};
#pragma unroll
                    for (int e = 0; e < 4; ++e) {
                        short hh, ll;
                        split_tr(vv[e], hh, ll);
                        int idx = q * 4 + e;
                        if (idx < 8) { h0[idx] = hh; l0[idx] = ll; }
                        else         { h1[idx - 8] = hh; l1[idx - 8] = ll; }
                    }
                }
            }
            *(s8v*)&As_h[srow][skq]     = h0;
            *(s8v*)&As_h[srow][skq + 8] = h1;
            *(s8v*)&As_l[srow][skq]     = l0;
            *(s8v*)&As_l[srow][skq + 8] = l1;
        }
        // ---- stage B (pre-split, contiguous) ----
        {
            s8v h0 = 0, h1 = 0, l0 = 0, l1 = 0;
            int gn = bn + srow;
            if (gn < N) {
                const s8v* ph = (const s8v*)(Bh + (size_t)gn * K + k0 + skq);
                const s8v* pl = (const s8v*)(Bl + (size_t)gn * K + k0 + skq);
                h0 = ph[0]; h1 = ph[1];
                l0 = pl[0]; l1 = pl[1];
            }
            *(s8v*)&Bs_h[srow][skq]     = h0;
            *(s8v*)&Bs_h[srow][skq + 8] = h1;
            *(s8v*)&Bs_l[srow][skq]     = l0;
            *(s8v*)&Bs_l[srow][skq + 8] = l1;
        }
        __syncthreads();

        s8v a_h[4], a_l[4], b_h[4], b_l[4];
#pragma unroll
        for (int m = 0; m < 4; ++m) {
            a_h[m] = *(const s8v*)&As_h[wr * 64 + m * 16 + fr][fg * 8];
            a_l[m] = *(const s8v*)&As_l[wr * 64 + m * 16 + fr][fg * 8];
        }
#pragma unroll
        for (int n = 0; n < 4; ++n) {
            b_h[n] = *(const s8v*)&Bs_h[wc * 64 + n * 16 + fr][fg * 8];
            b_l[n] = *(const s8v*)&Bs_l[wc * 64 + n * 16 + fr][fg * 8];
        }
#pragma unroll
        for (int m = 0; m < 4; ++m)
#pragma unroll
            for (int n = 0; n < 4; ++n) {
                f32x4 c = acc[m][n];
                c = __builtin_amdgcn_mfma_f32_16x16x32_bf16(a_l[m], b_h[n], c, 0, 0, 0);
                c = __builtin_amdgcn_mfma_f32_16x16x32_bf16(a_h[m], b_l[n], c, 0, 0, 0);
                c = __builtin_amdgcn_mfma_f32_16x16x32_bf16(a_h[m], b_h[n], c, 0, 0, 0);
                acc[m][n] = c;
            }
        __syncthreads();
    }

    // ---- epilogue: D[row=4*(l>>4)+r][col=l&15] ----
#pragma unroll
    for (int n = 0; n < 4; ++n) {
        int gcol = bn + wc * 64 + n * 16 + fr;
        float bv = bias[gcol];
#pragma unroll
        for (int m = 0; m < 4; ++m) {
            int rbase = bm + wr * 64 + m * 16 + fg * 4;
#pragma unroll
            for (int r = 0; r < 4; ++r) {
                int gm = rbase + r;
                if (gm < M) {
                    float v = acc[m][n][r] + bv;
                    if (RELU) v = fmaxf(v, 0.f);
                    C[(size_t)gm * N + gcol] = v;
                }
            }
        }
    }
}

// ---------------------------------------------------------------------------
// weight prep
// ---------------------------------------------------------------------------
// transpose + split: src (K,N) fp32 -> dh/dl (N,K) bf16
__global__ __launch_bounds__(256) void tsplit(const float* __restrict__ src,
                                              short* __restrict__ dh,
                                              short* __restrict__ dl,
                                              int Kd, int Nd)
{
    __shared__ float t[32][33];
    int tx = threadIdx.x & 31, ty = threadIdx.x >> 5;
    int n0 = blockIdx.x * 32, k0 = blockIdx.y * 32;
#pragma unroll
    for (int i = 0; i < 4; ++i)
        t[ty + 8 * i][tx] = src[(size_t)(k0 + ty + 8 * i) * Nd + n0 + tx];
    __syncthreads();
#pragma unroll
    for (int i = 0; i < 4; ++i) {
        int n = n0 + ty + 8 * i, k = k0 + tx;
        short h, l;
        split_rn(t[tx][ty + 8 * i], h, l);
        dh[(size_t)n * Kd + k] = h;
        dl[(size_t)n * Kd + k] = l;
    }
}

// plain split (already N,K layout): w_ih / w_hh
__global__ __launch_bounds__(256) void splitw(const float* __restrict__ x,
                                              short* __restrict__ h,
                                              short* __restrict__ l, int n)
{
    int i = (blockIdx.x * 256 + threadIdx.x) * 4;
    if (i < n) {
        float4 v = *(const float4*)(x + i);
        float vv[4] = {v.x, v.y, v.z, v.w};
        s4v hh, ll;
#pragma unroll
        for (int e = 0; e < 4; ++e) { short a, b; split_rn(vv[e], a, b); hh[e] = a; ll[e] = b; }
        *(s4v*)(h + i) = hh;
        *(s4v*)(l + i) = ll;
    }
}

// ---------------------------------------------------------------------------
// glue kernels
// ---------------------------------------------------------------------------
__global__ void score_softmax(const float* __restrict__ ps, float* __restrict__ sc)
{
    int lane = threadIdx.x;
    float x = ps[lane];
    float m = x;
    for (int off = 32; off; off >>= 1) m = fmaxf(m, __shfl_xor(m, off));
    float e = expf(x - m);
    float s = e;
    for (int off = 32; off; off >>= 1) s += __shfl_xor(s, off);
    sc[lane] = e / s;
}

__global__ __launch_bounds__(256) void wt_kernel(const int* __restrict__ ts,
                                                 const float* __restrict__ sc,
                                                 float* __restrict__ wt)
{
    __shared__ int ss[64], se[64];
    __shared__ float sw[64];
    int tid = threadIdx.x;
    if (tid < 64) {
        int s = ts[2 * tid];
        int e = ts[2 * tid + 1];
        if (e < s + 1) e = s + 1;
        ss[tid] = s; se[tid] = e;
        sw[tid] = sc[tid] / (float)(e - s);
    }
    __syncthreads();
    int t = blockIdx.x * 256 + tid;
    if (t < T_FRAMES) {
        float w = 0.f;
#pragma unroll
        for (int p = 0; p < 64; ++p)
            if (t >= ss[p] && t < se[p]) w += sw[p];
        wt[t] = w;
    }
}

// weighted partial reduce of video hidden rows (64-row chunks, 256 blocks)
__global__ __launch_bounds__(256) void upart_kernel(const float* __restrict__ H1,
                                                    const float* __restrict__ wt,
                                                    float* __restrict__ upart)
{
    int tid = threadIdx.x;
    int t0 = blockIdx.x * 64;
    float acc[4] = {0.f, 0.f, 0.f, 0.f};
    for (int t = 0; t < 64; ++t) {
        float w = wt[t0 + t];
        const float* row = H1 + (size_t)(t0 + t) * VD;
#pragma unroll
        for (int c = 0; c < 4; ++c)
            acc[c] = fmaf(w, row[tid + c * 256], acc[c]);
    }
#pragma unroll
    for (int c = 0; c < 4; ++c)
        upart[(size_t)blockIdx.x * VD + tid + c * 256] = acc[c];
}

__global__ __launch_bounds__(256) void ureduce2(const float* __restrict__ upart,
                                                float* __restrict__ u)
{
    int col = blockIdx.x * 256 + threadIdx.x;
    float acc = 0.f;
    for (int b = 0; b < 256; ++b) acc += upart[(size_t)b * VD + col];
    u[col] = acc;
}

// video_seg via pre-split transposed wv2: one wave per output j
__global__ __launch_bounds__(256) void videoseg_bt(const float* __restrict__ u,
                                                   const short* __restrict__ wh,
                                                   const short* __restrict__ wl,
                                                   const float* __restrict__ bv2,
                                                   float* __restrict__ vseg)
{
    int j = blockIdx.x * 4 + (threadIdx.x >> 6);
    int lane = threadIdx.x & 63;
    const s8v* ph = (const s8v*)(wh + (size_t)j * VD + lane * 16);
    const s8v* pl = (const s8v*)(wl + (size_t)j * VD + lane * 16);
    const float4* pu = (const float4*)(u + lane * 16);
    float acc = 0.f;
#pragma unroll
    for (int q = 0; q < 2; ++q) {
        s8v h = ph[q], l = pl[q];
        float4 u0 = pu[q * 2], u1 = pu[q * 2 + 1];
        float uu[8] = {u0.x, u0.y, u0.z, u0.w, u1.x, u1.y, u1.z, u1.w};
#pragma unroll
        for (int e = 0; e < 8; ++e)
            acc = fmaf(uu[e], bf2f(h[e]) + bf2f(l[e]), acc);
    }
    for (int off = 32; off; off >>= 1) acc += __shfl_xor(acc, off);
    if (lane == 0) vseg[j] = acc + bv2[j];
}

__global__ __launch_bounds__(256) void textseg_kernel(const float* __restrict__ sc,
                                                      const float* __restrict__ T2,
                                                      float* __restrict__ tseg)
{
    int j = threadIdx.x;
    float acc = 0.f;
    for (int p = 0; p < 64; ++p) acc = fmaf(sc[p], T2[(size_t)p * TO + j], acc);
    tseg[j] = acc;
}

__global__ __launch_bounds__(256) void copy_xt(const float* __restrict__ para,
                                               const float* __restrict__ question,
                                               const float* __restrict__ atexts,
                                               float* __restrict__ Xt)
{
    size_t total = (size_t)NTXT * TD;
    for (size_t id = (size_t)blockIdx.x * 256 + threadIdx.x; id < total;
         id += (size_t)gridDim.x * 256) {
        int r = (int)(id / TD);
        int c = (int)(id - (size_t)r * TD);
        float v;
        if (r < 64)       v = para[(size_t)r * TD + c];
        else if (r == 64) v = question[c];
        else              v = atexts[(size_t)(r - 65) * TD + c];
        Xt[id] = v;
    }
}

__global__ __launch_bounds__(256) void xp_build(const float* __restrict__ vseg,
                                                const float* __restrict__ tseg,
                                                const float* __restrict__ T2,
                                                const float* __restrict__ btn,
                                                float* __restrict__ Xp)
{
    size_t total = (size_t)2048 * 1024;
    for (size_t id = (size_t)blockIdx.x * 256 + threadIdx.x; id < total;
         id += (size_t)gridDim.x * 256) {
        int r = (int)(id >> 10);
        int c = (int)(id & 1023);
        float v;
        if (c < 256)      v = vseg[c];
        else if (c < 512) v = tseg[c - 256];
        else if (c < 768) v = T2[(size_t)64 * TO + (c - 512)] +
                              T2[(size_t)(65 + r) * TO + (c - 512)];
        else              v = btn[(size_t)r * VO + (c - 768)];
        Xp[id] = v;
    }
}

__global__ __launch_bounds__(256) void asc_build(const float* __restrict__ state0,
                                                 const float* __restrict__ IP,
                                                 float* __restrict__ ASC)
{
    size_t total = (size_t)NASC * HH;
    for (size_t id = (size_t)blockIdx.x * 256 + threadIdx.x; id < total;
         id += (size_t)gridDim.x * 256) {
        int r = (int)(id >> 9);
        int c = (int)(id & 511);
        ASC[id] = (r == 0) ? state0[c] : IP[(size_t)(r - 1) * HH + c];
    }
}

__device__ __forceinline__ float sigm(float x) { return 1.f / (1.f + expf(-x)); }

__global__ __launch_bounds__(256) void hn_build(const float* __restrict__ GI,
                                                const float* __restrict__ GH,
                                                const float* __restrict__ ASC,
                                                float* __restrict__ HN)
{
    size_t total = (size_t)NCAND * HH;
    for (size_t id = (size_t)blockIdx.x * 256 + threadIdx.x; id < total;
         id += (size_t)gridDim.x * 256) {
        int r = (int)(id >> 9);
        int c = (int)(id & 511);
        int crow, girow;
        if (r < 16) { crow = 0; girow = r; }
        else {
            int rr = r - 16;
            int k  = 1 + (rr >> 8);
            int rem = rr & 255;
            int ci = rem >> 4;
            int a  = rem & 15;
            crow = 1 + (k - 1) * 16 + ci;
            girow = k * 16 + a;
        }
        const float* gi = GI + (size_t)girow * (3 * HH);
        const float* gh = GH + (size_t)crow * (3 * HH);
        float ir = gi[c], iz = gi[512 + c], inn = gi[1024 + c];
        float hr = gh[c], hz = gh[512 + c], hn = gh[1024 + c];
        float h  = ASC[(size_t)crow * HH + c];
        float rg = sigm(ir + hr);
        float z  = sigm(iz + hz);
        float n  = tanhf(inn + rg * hn);
        HN[id] = (1.f - z) * n + z * h;
    }
}

__global__ __launch_bounds__(256) void lg_kernel(const float* __restrict__ L1,
                                                 const float* __restrict__ wj2,
                                                 const float* __restrict__ bj2,
                                                 float* __restrict__ LG)
{
    __shared__ float w[512];
    int tid = threadIdx.x;
    w[tid] = wj2[tid];
    w[tid + 256] = wj2[tid + 256];
    __syncthreads();
    int wave = tid >> 6, lane = tid & 63;
    float b = bj2[0];
    for (int r = blockIdx.x * 4 + wave; r < NCAND; r += gridDim.x * 4) {
        const float* row = L1 + (size_t)r * HH;
        float acc = 0.f;
#pragma unroll
        for (int q = 0; q < 8; ++q)
            acc = fmaf(row[lane + q * 64], w[lane + q * 64], acc);
        for (int off = 32; off; off >>= 1) acc += __shfl_xor(acc, off);
        if (lane == 0) LG[r] = acc + b;
    }
}

__global__ void chase_kernel(const float* __restrict__ LG, float* __restrict__ out)
{
    int lane = threadIdx.x;      // 64 threads
    int base = 0;
    for (int k = 0; k < S_N; ++k) {
        float v = -INFINITY;
        if (lane < 16) {
            v = LG[base + lane];
            out[k * 16 + lane] = v;
        }
        int bi = lane;
        for (int off = 8; off >= 1; off >>= 1) {
            float ov = __shfl_xor(v, off);
            int   oi = __shfl_xor(bi, off);
            if (ov > v || (ov == v && oi < bi)) { v = ov; bi = oi; }
        }
        int ci = __shfl(bi, 0);
        base = 16 + k * 256 + ci * 16;
    }
}

// ---------------------------------------------------------------------------
extern "C" void kernel_launch(void* const* d_in, const int* in_sizes, int n_in,
                              void* d_out, int out_size, void* d_ws, size_t ws_size,
                              hipStream_t stream)
{
    const float* video      = (const float*)d_in[0];
    const float* para       = (const float*)d_in[1];
    const float* question   = (const float*)d_in[2];
    const float* paras_scr  = (const float*)d_in[3];
    const float* a_texts    = (const float*)d_in[4];
    const float* a_buttons  = (const float*)d_in[5];
    const int*   timestamps = (const int*)d_in[6];
    const float* wv1 = (const float*)d_in[7];
    const float* bv1 = (const float*)d_in[8];
    const float* wv2 = (const float*)d_in[9];
    const float* bv2 = (const float*)d_in[10];
    const float* wt1 = (const float*)d_in[11];
    const float* bt1 = (const float*)d_in[12];
    const float* wt2 = (const float*)d_in[13];
    const float* bt2 = (const float*)d_in[14];
    const float* wp1 = (const float*)d_in[15];
    const float* bp1 = (const float*)d_in[16];
    const float* wp2 = (const float*)d_in[17];
    const float* bp2 = (const float*)d_in[18];
    const float* w_ih = (const float*)d_in[19];
    const float* b_ih = (const float*)d_in[20];
    const float* w_hh = (const float*)d_in[21];
    const float* b_hh = (const float*)d_in[22];
    const float* wj1 = (const float*)d_in[23];
    const float* bj1 = (const float*)d_in[24];
    const float* wj2 = (const float*)d_in[25];
    const float* bj2 = (const float*)d_in[26];
    const float* state0 = (const float*)d_in[27];

    char* wsb = (char*)d_ws;
    size_t off = 0;
    auto alloc = [&](size_t bytes) -> char* {
        size_t o = (off + 255) & ~(size_t)255;
        off = o + bytes;
        return wsb + o;
    };
    auto allocF = [&](size_t n) -> float* { return (float*)alloc(n * 4); };
    auto allocS = [&](size_t n) -> short* { return (short*)alloc(n * 2); };

    float* sc    = allocF(64);
    float* wtb   = allocF(T_FRAMES);
    float* u     = allocF(VD);
    float* upart = allocF((size_t)256 * VD);
    float* vseg  = allocF(VO);
    float* tseg  = allocF(TO);
    float* H1    = allocF((size_t)18432 * VD);      // video+buttons hidden; later L1
    float* Xt    = allocF((size_t)NTXT * TD);       // + T1 span -> later GI
    float* T1    = allocF((size_t)NTXT * TD);
    float* T2m   = allocF((size_t)NTXT * TO);       // + btn + Xp span -> later GH
    float* btn   = allocF((size_t)2048 * VO);
    float* Xp    = allocF((size_t)2048 * 1024);
    float* P1    = allocF((size_t)2048 * 1024);
    float* IP    = allocF((size_t)2048 * HH);
    float* ASC   = allocF((size_t)NASC * HH);
    float* HN    = allocF((size_t)NCAND * HH);
    float* LG    = allocF(NCAND);
    float* GI    = Xt;    // 2048*1536 <= 2*NTXT*768  (dead after G4)
    float* GH    = T2m;   // 2049*1536 <= T2m+btn+Xp span (dead after G5)
    float* L1    = H1;    // 32528*512 <= 18432*1024 (dead after upart + G2)

    short* wv1Th = allocS((size_t)VD * VD);   short* wv1Tl = allocS((size_t)VD * VD);
    short* wt1Th = allocS((size_t)TD * TD);   short* wt1Tl = allocS((size_t)TD * TD);
    short* wt2Th = allocS((size_t)TO * TD);   short* wt2Tl = allocS((size_t)TO * TD);
    short* wv2Th = allocS((size_t)VO * VD);   short* wv2Tl = allocS((size_t)VO * VD);
    short* wp1Th = allocS((size_t)1024 * 1024); short* wp1Tl = allocS((size_t)1024 * 1024);
    short* wp2Th = allocS((size_t)HH * 1024); short* wp2Tl = allocS((size_t)HH * 1024);
    short* wj1Th = allocS((size_t)HH * HH);   short* wj1Tl = allocS((size_t)HH * HH);
    short* wihSh = allocS((size_t)1536 * HH); short* wihSl = allocS((size_t)1536 * HH);
    short* whhSh = allocS((size_t)1536 * HH); short* whhSl = allocS((size_t)1536 * HH);

    // ---- weight prep ----
    tsplit<<<dim3(VD / 32, VD / 32), 256, 0, stream>>>(wv1, wv1Th, wv1Tl, VD, VD);
    tsplit<<<dim3(TD / 32, TD / 32), 256, 0, stream>>>(wt1, wt1Th, wt1Tl, TD, TD);
    tsplit<<<dim3(TO / 32, TD / 32), 256, 0, stream>>>(wt2, wt2Th, wt2Tl, TD, TO);
    tsplit<<<dim3(VO / 32, VD / 32), 256, 0, stream>>>(wv2, wv2Th, wv2Tl, VD, VO);
    tsplit<<<dim3(1024 / 32, 1024 / 32), 256, 0, stream>>>(wp1, wp1Th, wp1Tl, 1024, 1024);
    tsplit<<<dim3(HH / 32, 1024 / 32), 256, 0, stream>>>(wp2, wp2Th, wp2Tl, 1024, HH);
    tsplit<<<dim3(HH / 32, HH / 32), 256, 0, stream>>>(wj1, wj1Th, wj1Tl, HH, HH);
    splitw<<<(1536 * HH) / 1024, 256, 0, stream>>>(w_ih, wihSh, wihSl, 1536 * HH);
    splitw<<<(1536 * HH) / 1024, 256, 0, stream>>>(w_hh, whhSh, whhSl, 1536 * HH);

    // ---- small prep ----
    score_softmax<<<1, 64, 0, stream>>>(paras_scr, sc);
    wt_kernel<<<T_FRAMES / 256, 256, 0, stream>>>(timestamps, sc, wtb);

    // G1: merged video+buttons layer-1 (M=18432)
    mgemm<true><<<dim3(VD / 128, 18432 / 128), 256, 0, stream>>>(
        video, a_buttons, 16384, wv1Th, wv1Tl, bv1, H1, 18432, VD, VD);

    upart_kernel<<<256, 256, 0, stream>>>(H1, wtb, upart);
    ureduce2<<<VD / 256, 256, 0, stream>>>(upart, u);
    videoseg_bt<<<VO / 4, 256, 0, stream>>>(u, wv2Th, wv2Tl, bv2, vseg);

    // G2: btn = buttonsH @ wv2 + bv2
    mgemm<false><<<dim3(VO / 128, 2048 / 128), 256, 0, stream>>>(
        H1 + (size_t)16384 * VD, H1, 1 << 30, wv2Th, wv2Tl, bv2, btn, 2048, VO, VD);

    copy_xt<<<2048, 256, 0, stream>>>(para, question, a_texts, Xt);
    // G3/G4: text MLP
    mgemm<true><<<dim3(TD / 128, (NTXT + 127) / 128), 256, 0, stream>>>(
        Xt, Xt, 1 << 30, wt1Th, wt1Tl, bt1, T1, NTXT, TD, TD);
    mgemm<false><<<dim3(TO / 128, (NTXT + 127) / 128), 256, 0, stream>>>(
        T1, T1, 1 << 30, wt2Th, wt2Tl, bt2, T2m, NTXT, TO, TD);
    textseg_kernel<<<1, 256, 0, stream>>>(sc, T2m, tseg);

    xp_build<<<2048, 256, 0, stream>>>(vseg, tseg, T2m, btn, Xp);
    // G5/G6: pre-GRU MLP
    mgemm<true><<<dim3(1024 / 128, 2048 / 128), 256, 0, stream>>>(
        Xp, Xp, 1 << 30, wp1Th, wp1Tl, bp1, P1, 2048, 1024, 1024);
    mgemm<false><<<dim3(HH / 128, 2048 / 128), 256, 0, stream>>>(
        P1, P1, 1 << 30, wp2Th, wp2Tl, bp2, IP, 2048, HH, 1024);

    asc_build<<<1024, 256, 0, stream>>>(state0, IP, ASC);
    // G7/G8: GRU gate GEMMs
    mgemm<false><<<dim3(1536 / 128, 2048 / 128), 256, 0, stream>>>(
        IP, IP, 1 << 30, wihSh, wihSl, b_ih, GI, 2048, 1536, HH);
    mgemm<false><<<dim3(1536 / 128, (NASC + 127) / 128), 256, 0, stream>>>(
        ASC, ASC, 1 << 30, whhSh, whhSl, b_hh, GH, NASC, 1536, HH);

    hn_build<<<4096, 256, 0, stream>>>(GI, GH, ASC, HN);
    // G9: judge layer 1
    mgemm<true><<<dim3(HH / 128, (NCAND + 127) / 128), 256, 0, stream>>>(
        HN, HN, 1 << 30, wj1Th, wj1Tl, bj1, L1, NCAND, HH, HH);

    lg_kernel<<<512, 256, 0, stream>>>(L1, wj2, bj2, LG);
    chase_kernel<<<1, 64, 0, stream>>>(LG, (float*)d_out);
}

// Round 3
// 784.848 us; speedup vs baseline: 2.7307x; 1.1588x over previous
//
#include <hip/hip_runtime.h>
#include <math.h>

#define T_FRAMES 16384
#define S_N   128
#define VD    1024
#define VO    256
#define TD    768
#define TO    256
#define HH    512
#define NTXT  2113            // 64 para + 1 question + 2048 a_texts
#define NCAND 32528           // 16 + 127*256 candidate rows
#define NASC  2049            // state0 + 2048 inputs_pre rows
#define MVB   18432           // video 16384 + buttons 2048

typedef __attribute__((ext_vector_type(8))) short s8v;
typedef __attribute__((ext_vector_type(4))) float f32x4;

__device__ __forceinline__ float bf2f(short h) {
    return __builtin_bit_cast(float, ((unsigned)(unsigned short)h) << 16);
}
// round-to-nearest-even two-term split
__device__ __forceinline__ void split_rn(float v, short& h, short& l) {
    unsigned u = __builtin_bit_cast(unsigned, v);
    unsigned short uh = (unsigned short)((u + 0x7fff + ((u >> 16) & 1)) >> 16);
    float lf = v - bf2f((short)uh);
    unsigned ul = __builtin_bit_cast(unsigned, lf);
    unsigned short us = (unsigned short)((ul + 0x7fff + ((ul >> 16) & 1)) >> 16);
    h = (short)uh; l = (short)us;
}

__device__ __forceinline__ void gload16(const void* g, void* l) {
    __builtin_amdgcn_global_load_lds(
        (const __attribute__((address_space(1))) unsigned int*)g,
        (__attribute__((address_space(3))) unsigned int*)l, 16, 0, 0);
}

// ---------------------------------------------------------------------------
// bf16-split MFMA GEMM, all operands pre-split bf16 hi/lo.
//  A: (M,K) row-major hi/lo.  B: (N,K) row-major hi/lo (i.e. B^T).
//  128x128 tile, BK=32, 256 thr (4 waves 2x2), 4x4 16x16x32 frags, 3 MFMA/frag.
//  Staging: global_load_lds 16B, LDS linear, XOR granule swizzle on the SOURCE
//  address; ds_read applies the same XOR -> conflict-floor reads.
//  MODE: 0 plain split-store, 1 +relu, 2 G1 (video rows -> weighted u-atomic,
//  button rows -> relu split-store), 3 G9 (relu -> .wj2 dot -> LG atomic).
// ---------------------------------------------------------------------------
template<int MODE>
__global__ __launch_bounds__(256, 3) void mgemm2(
    const short* __restrict__ Ah, const short* __restrict__ Al,
    const short* __restrict__ Bh, const short* __restrict__ Bl,
    const float* __restrict__ bias,
    short* __restrict__ Ch, short* __restrict__ Cl,
    const float* __restrict__ wt, float* __restrict__ uacc,
    const float* __restrict__ wj2, float* __restrict__ LG,
    int M, int N, int K, int gx)
{
    __shared__ __align__(16) short As_h[4096], As_l[4096], Bs_h[4096], Bs_l[4096];

    const int tid = threadIdx.x;
    // bijective XCD-aware block swizzle
    const int nwg = gridDim.x;
    const int orig = blockIdx.x;
    const int q = nwg >> 3, r8 = nwg & 7, xcd = orig & 7, ridx = orig >> 3;
    const int swz = (xcd < r8 ? xcd * (q + 1) : r8 * (q + 1) + (xcd - r8) * q) + ridx;
    const int bm = (swz / gx) * 128;
    const int bn = (swz % gx) * 128;

    const int w = tid >> 6, l = tid & 63;
    const int fr = l & 15, fg = l >> 4;
    const int wr = w >> 1, wc = w & 1;

    // staging geometry: granule g = i*256 + w*64 + l ; row = g>>2, c = g&3
    const int g0 = w * 64 + l;
    const int r0 = g0 >> 2, c0 = g0 & 3;
    const int cs = c0 ^ ((r0 >> 1) & 3);          // same for row r0 and r0+64
    int ra0 = bm + r0;          if (ra0 > M - 1) ra0 = M - 1;
    int ra1 = bm + r0 + 64;     if (ra1 > M - 1) ra1 = M - 1;
    const size_t aoff0 = (size_t)ra0 * K + (cs << 3);
    const size_t aoff1 = (size_t)ra1 * K + (cs << 3);
    const size_t boff0 = (size_t)(bn + r0) * K + (cs << 3);
    const size_t boff1 = (size_t)(bn + r0 + 64) * K + (cs << 3);
    const int ldsb0 = (w * 64) * 8;               // short index of wave dest
    const int ldsb1 = (256 + w * 64) * 8;

    // fragment LDS offsets (short index), with the matching XOR
    int offA[4], offB[4];
#pragma unroll
    for (int m = 0; m < 4; ++m) {
        int row = wr * 64 + m * 16 + fr;
        offA[m] = row * 32 + ((fg ^ ((row >> 1) & 3)) << 3);
        int col = wc * 64 + m * 16 + fr;
        offB[m] = col * 32 + ((fg ^ ((col >> 1) & 3)) << 3);
    }

    f32x4 acc[4][4];
#pragma unroll
    for (int m = 0; m < 4; ++m)
#pragma unroll
        for (int n = 0; n < 4; ++n) acc[m][n] = (f32x4){0.f, 0.f, 0.f, 0.f};

    for (int k0 = 0; k0 < K; k0 += 32) {
        gload16(Ah + aoff0 + k0, &As_h[ldsb0]);
        gload16(Ah + aoff1 + k0, &As_h[ldsb1]);
        gload16(Al + aoff0 + k0, &As_l[ldsb0]);
        gload16(Al + aoff1 + k0, &As_l[ldsb1]);
        gload16(Bh + boff0 + k0, &Bs_h[ldsb0]);
        gload16(Bh + boff1 + k0, &Bs_h[ldsb1]);
        gload16(Bl + boff0 + k0, &Bs_l[ldsb0]);
        gload16(Bl + boff1 + k0, &Bs_l[ldsb1]);
        __syncthreads();   // compiler drains vmcnt before barrier

        s8v ah[4], al[4];
#pragma unroll
        for (int m = 0; m < 4; ++m) {
            ah[m] = *(const s8v*)&As_h[offA[m]];
            al[m] = *(const s8v*)&As_l[offA[m]];
        }
#pragma unroll
        for (int n = 0; n < 4; ++n) {
            s8v bh = *(const s8v*)&Bs_h[offB[n]];
            s8v bl = *(const s8v*)&Bs_l[offB[n]];
#pragma unroll
            for (int m = 0; m < 4; ++m) {
                f32x4 c = acc[m][n];
                c = __builtin_amdgcn_mfma_f32_16x16x32_bf16(al[m], bh, c, 0, 0, 0);
                c = __builtin_amdgcn_mfma_f32_16x16x32_bf16(ah[m], bl, c, 0, 0, 0);
                c = __builtin_amdgcn_mfma_f32_16x16x32_bf16(ah[m], bh, c, 0, 0, 0);
                acc[m][n] = c;
            }
        }
        __syncthreads();
    }

    // ---------------- epilogues ----------------
    if (MODE == 2 && bm < 16384) {
        // weighted column reduction of relu(acc+bias) into u
        float wtv[4][4];
#pragma unroll
        for (int m = 0; m < 4; ++m)
#pragma unroll
            for (int r = 0; r < 4; ++r)
                wtv[m][r] = wt[bm + wr * 64 + m * 16 + fg * 4 + r];
#pragma unroll
        for (int n = 0; n < 4; ++n) {
            int gcol = bn + wc * 64 + n * 16 + fr;
            float bv = bias[gcol];
            float s = 0.f;
#pragma unroll
            for (int m = 0; m < 4; ++m)
#pragma unroll
                for (int r = 0; r < 4; ++r)
                    s += fmaxf(acc[m][n][r] + bv, 0.f) * wtv[m][r];
            s += __shfl_xor(s, 16);
            s += __shfl_xor(s, 32);
            if (fg == 0) atomicAdd(&uacc[gcol], s);
        }
        return;
    }
    if (MODE == 3) {
        // LG[row] += sum_col relu(acc+bj1[col]) * wj2[col]
#pragma unroll
        for (int m = 0; m < 4; ++m) {
            float s0 = 0.f, s1 = 0.f, s2 = 0.f, s3 = 0.f;
#pragma unroll
            for (int n = 0; n < 4; ++n) {
                int gcol = bn + wc * 64 + n * 16 + fr;
                float bv = bias[gcol], w2 = wj2[gcol];
                s0 += fmaxf(acc[m][n][0] + bv, 0.f) * w2;
                s1 += fmaxf(acc[m][n][1] + bv, 0.f) * w2;
                s2 += fmaxf(acc[m][n][2] + bv, 0.f) * w2;
                s3 += fmaxf(acc[m][n][3] + bv, 0.f) * w2;
            }
            float sv[4] = {s0, s1, s2, s3};
#pragma unroll
            for (int r = 0; r < 4; ++r) {
                float v = sv[r];
                v += __shfl_xor(v, 1); v += __shfl_xor(v, 2);
                v += __shfl_xor(v, 4); v += __shfl_xor(v, 8);
                int gm = bm + wr * 64 + m * 16 + fg * 4 + r;
                if (fr == 0 && gm < M) atomicAdd(&LG[gm], v);
            }
        }
        return;
    }
    {
        const int rowoff = (MODE == 2) ? 16384 : 0;
#pragma unroll
        for (int n = 0; n < 4; ++n) {
            int gcol = bn + wc * 64 + n * 16 + fr;
            float bv = bias[gcol];
#pragma unroll
            for (int m = 0; m < 4; ++m) {
                int rbase = bm + wr * 64 + m * 16 + fg * 4;
#pragma unroll
                for (int r = 0; r < 4; ++r) {
                    int gm = rbase + r;
                    if (gm < M) {
                        float v = acc[m][n][r] + bv;
                        if (MODE == 1 || MODE == 2) v = fmaxf(v, 0.f);
                        short hh, ll; split_rn(v, hh, ll);
                        size_t o = (size_t)(gm - rowoff) * N + gcol;
                        Ch[o] = hh; Cl[o] = ll;
                    }
                }
            }
        }
    }
}

// ---------------------------------------------------------------------------
// one-shot weight prep: 7 transpose+split + 2 plain splits
// ---------------------------------------------------------------------------
struct PrepArgs {
    const float* src[9];
    short* dh[9]; short* dl[9];
    int K[9], N[9], tr[9];
};
__global__ __launch_bounds__(256) void prep_weights(PrepArgs a)
{
    const int wi = blockIdx.y;
    const float* src = a.src[wi];
    short* dh = a.dh[wi]; short* dl = a.dl[wi];
    const int K = a.K[wi], N = a.N[wi];
    __shared__ float t[32][33];
    if (a.tr[wi]) {
        int nb = N >> 5, kb = K >> 5;
        if ((int)blockIdx.x >= nb * kb) return;
        int tx = threadIdx.x & 31, ty = threadIdx.x >> 5;
        int n0 = ((int)blockIdx.x % nb) << 5, k0 = ((int)blockIdx.x / nb) << 5;
#pragma unroll
        for (int i = 0; i < 4; ++i)
            t[ty + 8 * i][tx] = src[(size_t)(k0 + ty + 8 * i) * N + n0 + tx];
        __syncthreads();
#pragma unroll
        for (int i = 0; i < 4; ++i) {
            int n = n0 + ty + 8 * i, k = k0 + tx;
            short h, l; split_rn(t[tx][ty + 8 * i], h, l);
            dh[(size_t)n * K + k] = h;
            dl[(size_t)n * K + k] = l;
        }
    } else {
        int total = K * N;
        int i0 = ((int)blockIdx.x * 256 + (int)threadIdx.x) * 4;
        if (i0 < total) {
            float4 v = *(const float4*)(src + i0);
            float vv[4] = {v.x, v.y, v.z, v.w};
#pragma unroll
            for (int e = 0; e < 4; ++e) {
                short h, l; split_rn(vv[e], h, l);
                dh[i0 + e] = h; dl[i0 + e] = l;
            }
        }
    }
}

// split video+buttons into one (18432,1024) bf16 pair
__global__ __launch_bounds__(256) void asplit_vb(const float* __restrict__ video,
                                                 const float* __restrict__ btns,
                                                 short* __restrict__ h,
                                                 short* __restrict__ l)
{
    const size_t vtotal = (size_t)16384 * VD;
    const size_t total = (size_t)MVB * VD;
    for (size_t i = ((size_t)blockIdx.x * 256 + threadIdx.x) * 4; i < total;
         i += (size_t)gridDim.x * 1024) {
        const float* s = (i < vtotal) ? video + i : btns + (i - vtotal);
        float4 v = *(const float4*)s;
        float vv[4] = {v.x, v.y, v.z, v.w};
#pragma unroll
        for (int e = 0; e < 4; ++e) {
            short hh, ll; split_rn(vv[e], hh, ll);
            h[i + e] = hh; l[i + e] = ll;
        }
    }
}

// prolog: paragraph softmax, zero u, split state0 -> ASC row0, LG = bj2
__global__ __launch_bounds__(256) void prolog(const float* __restrict__ ps,
                                              float* __restrict__ sc,
                                              float* __restrict__ u,
                                              const float* __restrict__ state0,
                                              short* __restrict__ ASCh,
                                              short* __restrict__ ASCl,
                                              const float* __restrict__ bj2,
                                              float* __restrict__ LG)
{
    int b = blockIdx.x, tid = threadIdx.x;
    if (b == 0) {
        if (tid < 64) {
            float x = ps[tid];
            float m = x;
            for (int off = 32; off; off >>= 1) m = fmaxf(m, __shfl_xor(m, off));
            float e = expf(x - m);
            float s = e;
            for (int off = 32; off; off >>= 1) s += __shfl_xor(s, off);
            sc[tid] = e / s;
        }
    } else if (b == 1) {
#pragma unroll
        for (int i = 0; i < 4; ++i) u[tid + i * 256] = 0.f;
    } else if (b == 2) {
#pragma unroll
        for (int i = 0; i < 2; ++i) {
            int c = tid + i * 256;
            short h, l; split_rn(state0[c], h, l);
            ASCh[c] = h; ASCl[c] = l;
        }
    } else {
        int i = (b - 3) * 256 + tid;
        if (i < NCAND) LG[i] = bj2[0];
    }
}

__global__ __launch_bounds__(256) void wt_kernel(const int* __restrict__ ts,
                                                 const float* __restrict__ sc,
                                                 float* __restrict__ wt)
{
    __shared__ int ss[64], se[64];
    __shared__ float sw[64];
    int tid = threadIdx.x;
    if (tid < 64) {
        int s = ts[2 * tid];
        int e = ts[2 * tid + 1];
        if (e < s + 1) e = s + 1;
        ss[tid] = s; se[tid] = e;
        sw[tid] = sc[tid] / (float)(e - s);
    }
    __syncthreads();
    int t = blockIdx.x * 256 + tid;
    if (t < T_FRAMES) {
        float w = 0.f;
#pragma unroll
        for (int p = 0; p < 64; ++p)
            if (t >= ss[p] && t < se[p]) w += sw[p];
        wt[t] = w;
    }
}

// video_seg = u @ wv2 + bv2 using split transposed wv2 (one wave per output)
__global__ __launch_bounds__(256) void videoseg_bt(const float* __restrict__ u,
                                                   const short* __restrict__ wh,
                                                   const short* __restrict__ wl,
                                                   const float* __restrict__ bv2,
                                                   float* __restrict__ vseg)
{
    int j = blockIdx.x * 4 + (threadIdx.x >> 6);
    int lane = threadIdx.x & 63;
    const s8v* ph = (const s8v*)(wh + (size_t)j * VD + lane * 16);
    const s8v* pl = (const s8v*)(wl + (size_t)j * VD + lane * 16);
    const float4* pu = (const float4*)(u + lane * 16);
    float acc = 0.f;
#pragma unroll
    for (int qq = 0; qq < 2; ++qq) {
        s8v h = ph[qq], l = pl[qq];
        float4 u0 = pu[qq * 2], u1 = pu[qq * 2 + 1];
        float uu[8] = {u0.x, u0.y, u0.z, u0.w, u1.x, u1.y, u1.z, u1.w};
#pragma unroll
        for (int e = 0; e < 8; ++e)
            acc = fmaf(uu[e], bf2f(h[e]) + bf2f(l[e]), acc);
    }
    for (int off = 32; off; off >>= 1) acc += __shfl_xor(acc, off);
    if (lane == 0) vseg[j] = acc + bv2[j];
}

__global__ __launch_bounds__(256) void textseg_kernel(const float* __restrict__ sc,
                                                      const short* __restrict__ T2h,
                                                      const short* __restrict__ T2l,
                                                      float* __restrict__ tseg)
{
    int j = threadIdx.x;
    float acc = 0.f;
    for (int p = 0; p < 64; ++p) {
        size_t o = (size_t)p * TO + j;
        acc = fmaf(sc[p], bf2f(T2h[o]) + bf2f(T2l[o]), acc);
    }
    tseg[j] = acc;
}

// stack [para; question; a_texts] -> split Xt (2113 x 768)
__global__ __launch_bounds__(256) void copy_xt_split(const float* __restrict__ para,
                                                     const float* __restrict__ question,
                                                     const float* __restrict__ atexts,
                                                     short* __restrict__ Xh,
                                                     short* __restrict__ Xl)
{
    size_t total = (size_t)NTXT * TD;
    for (size_t id = ((size_t)blockIdx.x * 256 + threadIdx.x) * 4; id < total;
         id += (size_t)gridDim.x * 1024) {
        int r = (int)(id / TD);
        int c = (int)(id - (size_t)r * TD);
        const float* s;
        if (r < 64)       s = para + (size_t)r * TD + c;
        else if (r == 64) s = question + c;
        else              s = atexts + (size_t)(r - 65) * TD + c;
        float4 v = *(const float4*)s;
        float vv[4] = {v.x, v.y, v.z, v.w};
#pragma unroll
        for (int e = 0; e < 4; ++e) {
            short h, l; split_rn(vv[e], h, l);
            Xh[id + e] = h; Xl[id + e] = l;
        }
    }
}

// Xp row r = [vseg | tseg | q + T2[65+r] | btn[r]] -> split (2048 x 1024)
__global__ __launch_bounds__(256) void xp_build_split(const float* __restrict__ vseg,
                                                      const float* __restrict__ tseg,
                                                      const short* __restrict__ T2h,
                                                      const short* __restrict__ T2l,
                                                      const short* __restrict__ btnh,
                                                      const short* __restrict__ btnl,
                                                      short* __restrict__ Xh,
                                                      short* __restrict__ Xl)
{
    size_t total = (size_t)2048 * 1024;
    for (size_t id = (size_t)blockIdx.x * 256 + threadIdx.x; id < total;
         id += (size_t)gridDim.x * 256) {
        int r = (int)(id >> 10);
        int c = (int)(id & 1023);
        short h, l;
        if (c < 256) {
            split_rn(vseg[c], h, l);
        } else if (c < 512) {
            split_rn(tseg[c - 256], h, l);
        } else if (c < 768) {
            size_t o1 = (size_t)64 * TO + (c - 512);
            size_t o2 = (size_t)(65 + r) * TO + (c - 512);
            float v = (bf2f(T2h[o1]) + bf2f(T2l[o1])) +
                      (bf2f(T2h[o2]) + bf2f(T2l[o2]));
            split_rn(v, h, l);
        } else {
            size_t o = (size_t)r * VO + (c - 768);
            h = btnh[o]; l = btnl[o];
        }
        Xh[id] = h; Xl[id] = l;
    }
}

__device__ __forceinline__ float sigm(float x) { return 1.f / (1.f + expf(-x)); }

// GRU gate fusion over all candidate rows (split in, split out)
__global__ __launch_bounds__(256) void hn_build(const short* __restrict__ GIh,
                                                const short* __restrict__ GIl,
                                                const short* __restrict__ GHh,
                                                const short* __restrict__ GHl,
                                                const short* __restrict__ ASCh,
                                                const short* __restrict__ ASCl,
                                                short* __restrict__ HNh,
                                                short* __restrict__ HNl)
{
    size_t total = (size_t)NCAND * HH;
    for (size_t id = (size_t)blockIdx.x * 256 + threadIdx.x; id < total;
         id += (size_t)gridDim.x * 256) {
        int r = (int)(id >> 9);
        int c = (int)(id & 511);
        int crow, girow;
        if (r < 16) { crow = 0; girow = r; }
        else {
            int rr = r - 16;
            int k  = 1 + (rr >> 8);
            int rem = rr & 255;
            int ci = rem >> 4;
            int a  = rem & 15;
            crow = 1 + (k - 1) * 16 + ci;
            girow = k * 16 + a;
        }
        size_t gi0 = (size_t)girow * 1536 + c;
        size_t gh0 = (size_t)crow * 1536 + c;
        float ir = bf2f(GIh[gi0])        + bf2f(GIl[gi0]);
        float iz = bf2f(GIh[gi0 + 512])  + bf2f(GIl[gi0 + 512]);
        float in = bf2f(GIh[gi0 + 1024]) + bf2f(GIl[gi0 + 1024]);
        float hr = bf2f(GHh[gh0])        + bf2f(GHl[gh0]);
        float hz = bf2f(GHh[gh0 + 512])  + bf2f(GHl[gh0 + 512]);
        float hn = bf2f(GHh[gh0 + 1024]) + bf2f(GHl[gh0 + 1024]);
        size_t ho = (size_t)crow * HH + c;
        float h  = bf2f(ASCh[ho]) + bf2f(ASCl[ho]);
        float rg = sigm(ir + hr);
        float z  = sigm(iz + hz);
        float n  = tanhf(in + rg * hn);
        float v  = (1.f - z) * n + z * h;
        short hh, ll; split_rn(v, hh, ll);
        HNh[id] = hh; HNl[id] = ll;
    }
}

// sequential pointer-chase (1 wave)
__global__ void chase_kernel(const float* __restrict__ LG, float* __restrict__ out)
{
    int lane = threadIdx.x;
    int base = 0;
    for (int k = 0; k < S_N; ++k) {
        float v = -INFINITY;
        if (lane < 16) {
            v = LG[base + lane];
            out[k * 16 + lane] = v;
        }
        int bi = lane;
        for (int off = 8; off >= 1; off >>= 1) {
            float ov = __shfl_xor(v, off);
            int   oi = __shfl_xor(bi, off);
            if (ov > v || (ov == v && oi < bi)) { v = ov; bi = oi; }
        }
        int ci = __shfl(bi, 0);
        base = 16 + k * 256 + ci * 16;
    }
}

// ---------------------------------------------------------------------------
extern "C" void kernel_launch(void* const* d_in, const int* in_sizes, int n_in,
                              void* d_out, int out_size, void* d_ws, size_t ws_size,
                              hipStream_t stream)
{
    const float* video      = (const float*)d_in[0];
    const float* para       = (const float*)d_in[1];
    const float* question   = (const float*)d_in[2];
    const float* paras_scr  = (const float*)d_in[3];
    const float* a_texts    = (const float*)d_in[4];
    const float* a_buttons  = (const float*)d_in[5];
    const int*   timestamps = (const int*)d_in[6];
    const float* wv1 = (const float*)d_in[7];
    const float* bv1 = (const float*)d_in[8];
    const float* wv2 = (const float*)d_in[9];
    const float* bv2 = (const float*)d_in[10];
    const float* wt1 = (const float*)d_in[11];
    const float* bt1 = (const float*)d_in[12];
    const float* wt2 = (const float*)d_in[13];
    const float* bt2 = (const float*)d_in[14];
    const float* wp1 = (const float*)d_in[15];
    const float* bp1 = (const float*)d_in[16];
    const float* wp2 = (const float*)d_in[17];
    const float* bp2 = (const float*)d_in[18];
    const float* w_ih = (const float*)d_in[19];
    const float* b_ih = (const float*)d_in[20];
    const float* w_hh = (const float*)d_in[21];
    const float* b_hh = (const float*)d_in[22];
    const float* wj1 = (const float*)d_in[23];
    const float* bj1 = (const float*)d_in[24];
    const float* wj2 = (const float*)d_in[25];
    const float* bj2 = (const float*)d_in[26];
    const float* state0 = (const float*)d_in[27];

    char* wsb = (char*)d_ws;
    size_t off = 0;
    auto alloc = [&](size_t bytes) -> char* {
        size_t o = (off + 255) & ~(size_t)255;
        off = o + bytes;
        return wsb + o;
    };
    auto allocF = [&](size_t n) -> float* { return (float*)alloc(n * 4); };
    auto allocS = [&](size_t n) -> short* { return (short*)alloc(n * 2); };

    float* sc   = allocF(64);
    float* wtb  = allocF(T_FRAMES);
    float* u    = allocF(VD);
    float* vseg = allocF(VO);
    float* tseg = allocF(TO);
    float* LG   = allocF(NCAND);

    short* Avbh = allocS((size_t)MVB * VD);       // later reused as HNh
    short* Avbl = allocS((size_t)MVB * VD);       // later reused as HNl
    short* H1bh = allocS((size_t)2048 * VD);
    short* H1bl = allocS((size_t)2048 * VD);
    short* Xth  = allocS((size_t)NTXT * TD);
    short* Xtl  = allocS((size_t)NTXT * TD);
    short* T1h  = allocS((size_t)NTXT * TD);
    short* T1l  = allocS((size_t)NTXT * TD);
    short* T2h  = allocS((size_t)NTXT * TO);
    short* T2l  = allocS((size_t)NTXT * TO);
    short* btnh = allocS((size_t)2048 * VO);
    short* btnl = allocS((size_t)2048 * VO);
    short* Xph  = allocS((size_t)2048 * 1024);
    short* Xpl  = allocS((size_t)2048 * 1024);
    short* P1h  = allocS((size_t)2048 * 1024);
    short* P1l  = allocS((size_t)2048 * 1024);
    short* ASCh = allocS((size_t)NASC * HH);
    short* ASCl = allocS((size_t)NASC * HH);
    short* GIh  = allocS((size_t)2048 * 1536);
    short* GIl  = allocS((size_t)2048 * 1536);
    short* GHh  = allocS((size_t)NASC * 1536);
    short* GHl  = allocS((size_t)NASC * 1536);
    short* IPh  = ASCh + HH;                      // IP = ASC rows 1..2048
    short* IPl  = ASCl + HH;
    short* HNh  = Avbh;                           // Avb dead after G1
    short* HNl  = Avbl;

    short* wv1Th = allocS((size_t)VD * VD);   short* wv1Tl = allocS((size_t)VD * VD);
    short* wt1Th = allocS((size_t)TD * TD);   short* wt1Tl = allocS((size_t)TD * TD);
    short* wt2Th = allocS((size_t)TO * TD);   short* wt2Tl = allocS((size_t)TO * TD);
    short* wv2Th = allocS((size_t)VO * VD);   short* wv2Tl = allocS((size_t)VO * VD);
    short* wp1Th = allocS((size_t)1024 * 1024); short* wp1Tl = allocS((size_t)1024 * 1024);
    short* wp2Th = allocS((size_t)HH * 1024); short* wp2Tl = allocS((size_t)HH * 1024);
    short* wj1Th = allocS((size_t)HH * HH);   short* wj1Tl = allocS((size_t)HH * HH);
    short* wihSh = allocS((size_t)1536 * HH); short* wihSl = allocS((size_t)1536 * HH);
    short* whhSh = allocS((size_t)1536 * HH); short* whhSl = allocS((size_t)1536 * HH);

    // 1. prolog (softmax, zero u, ASC row0, LG=bj2)
    prolog<<<131, 256, 0, stream>>>(paras_scr, sc, u, state0, ASCh, ASCl, bj2, LG);
    // 2. frame weights
    wt_kernel<<<T_FRAMES / 256, 256, 0, stream>>>(timestamps, sc, wtb);
    // 3. all weight splits
    {
        PrepArgs pa;
        const float* s[9] = {wv1, wt1, wt2, wv2, wp1, wp2, wj1, w_ih, w_hh};
        short* dh[9] = {wv1Th, wt1Th, wt2Th, wv2Th, wp1Th, wp2Th, wj1Th, wihSh, whhSh};
        short* dl[9] = {wv1Tl, wt1Tl, wt2Tl, wv2Tl, wp1Tl, wp2Tl, wj1Tl, wihSl, whhSl};
        int K[9] = {VD, TD, TD, VD, 1024, 1024, HH, HH, HH};
        int N[9] = {VD, TD, TO, VO, 1024, HH, HH, 1536, 1536};
        int tr[9] = {1, 1, 1, 1, 1, 1, 1, 0, 0};
        for (int i = 0; i < 9; ++i) {
            pa.src[i] = s[i]; pa.dh[i] = dh[i]; pa.dl[i] = dl[i];
            pa.K[i] = K[i]; pa.N[i] = N[i]; pa.tr[i] = tr[i];
        }
        prep_weights<<<dim3(1024, 9), 256, 0, stream>>>(pa);
    }
    // 4. split video+buttons
    asplit_vb<<<4608, 256, 0, stream>>>(video, a_buttons, Avbh, Avbl);
    // 5. stack+split text rows
    copy_xt_split<<<1586, 256, 0, stream>>>(para, question, a_texts, Xth, Xtl);

    // G1: layer-1 over video+buttons; fused weighted u-reduction for video rows
    mgemm2<2><<<8 * 144, 256, 0, stream>>>(Avbh, Avbl, wv1Th, wv1Tl, bv1,
                                           H1bh, H1bl, wtb, u, nullptr, nullptr,
                                           MVB, VD, VD, 8);
    // video_seg
    videoseg_bt<<<VO / 4, 256, 0, stream>>>(u, wv2Th, wv2Tl, bv2, vseg);
    // G2: btn
    mgemm2<0><<<2 * 16, 256, 0, stream>>>(H1bh, H1bl, wv2Th, wv2Tl, bv2,
                                          btnh, btnl, nullptr, nullptr, nullptr, nullptr,
                                          2048, VO, VD, 2);
    // G3/G4: text MLP
    mgemm2<1><<<6 * 17, 256, 0, stream>>>(Xth, Xtl, wt1Th, wt1Tl, bt1,
                                          T1h, T1l, nullptr, nullptr, nullptr, nullptr,
                                          NTXT, TD, TD, 6);
    mgemm2<0><<<2 * 17, 256, 0, stream>>>(T1h, T1l, wt2Th, wt2Tl, bt2,
                                          T2h, T2l, nullptr, nullptr, nullptr, nullptr,
                                          NTXT, TO, TD, 2);
    textseg_kernel<<<1, 256, 0, stream>>>(sc, T2h, T2l, tseg);
    // concat
    xp_build_split<<<2048, 256, 0, stream>>>(vseg, tseg, T2h, T2l, btnh, btnl, Xph, Xpl);
    // G5/G6: pre-GRU MLP (G6 writes IP = ASC rows 1..)
    mgemm2<1><<<8 * 16, 256, 0, stream>>>(Xph, Xpl, wp1Th, wp1Tl, bp1,
                                          P1h, P1l, nullptr, nullptr, nullptr, nullptr,
                                          2048, 1024, 1024, 8);
    mgemm2<0><<<4 * 16, 256, 0, stream>>>(P1h, P1l, wp2Th, wp2Tl, bp2,
                                          IPh, IPl, nullptr, nullptr, nullptr, nullptr,
                                          2048, HH, 1024, 4);
    // G7/G8: GRU gate GEMMs
    mgemm2<0><<<12 * 16, 256, 0, stream>>>(IPh, IPl, wihSh, wihSl, b_ih,
                                           GIh, GIl, nullptr, nullptr, nullptr, nullptr,
                                           2048, 1536, HH, 12);
    mgemm2<0><<<12 * 17, 256, 0, stream>>>(ASCh, ASCl, whhSh, whhSl, b_hh,
                                           GHh, GHl, nullptr, nullptr, nullptr, nullptr,
                                           NASC, 1536, HH, 12);
    // gate fusion
    hn_build<<<4096, 256, 0, stream>>>(GIh, GIl, GHh, GHl, ASCh, ASCl, HNh, HNl);
    // G9: judge MLP fused to logits (atomic into LG)
    mgemm2<3><<<4 * 255, 256, 0, stream>>>(HNh, HNl, wj1Th, wj1Tl, bj1,
                                           nullptr, nullptr, nullptr, nullptr, wj2, LG,
                                           NCAND, HH, HH, 4);
    // path chase + output
    chase_kernel<<<1, 64, 0, stream>>>(LG, (float*)d_out);
}

// Round 4
// 656.918 us; speedup vs baseline: 3.2624x; 1.1947x over previous
//
#include <hip/hip_runtime.h>
#include <math.h>

#define T_FRAMES 16384
#define S_N   128
#define VD    1024
#define VO    256
#define TD    768
#define TO    256
#define HH    512
#define NTXT  2113            // 64 para + 1 question + 2048 a_texts
#define NCAND 32528           // 16 + 127*256 candidate rows
#define NGRP  2033            // NCAND / 16
#define NASC  2049            // state0 + 2048 inputs_pre rows
#define MVB   18432           // video 16384 + buttons 2048

typedef __attribute__((ext_vector_type(8))) short s8v;
typedef __attribute__((ext_vector_type(4))) short s4v;
typedef __attribute__((ext_vector_type(4))) float f32x4;

__device__ __forceinline__ float bf2f(short h) {
    return __builtin_bit_cast(float, ((unsigned)(unsigned short)h) << 16);
}
__device__ __forceinline__ void split_rn(float v, short& h, short& l) {
    unsigned u = __builtin_bit_cast(unsigned, v);
    unsigned short uh = (unsigned short)((u + 0x7fff + ((u >> 16) & 1)) >> 16);
    float lf = v - bf2f((short)uh);
    unsigned ul = __builtin_bit_cast(unsigned, lf);
    unsigned short us = (unsigned short)((ul + 0x7fff + ((ul >> 16) & 1)) >> 16);
    h = (short)uh; l = (short)us;
}
__device__ __forceinline__ void gload16(const void* g, void* l) {
    __builtin_amdgcn_global_load_lds(
        (const __attribute__((address_space(1))) unsigned int*)g,
        (__attribute__((address_space(3))) unsigned int*)l, 16, 0, 0);
}
__device__ __forceinline__ f32x4 ld4s(const short* __restrict__ H,
                                      const short* __restrict__ L, size_t o) {
    s4v h = *(const s4v*)(H + o);
    s4v l = *(const s4v*)(L + o);
    return (f32x4){bf2f(h[0]) + bf2f(l[0]), bf2f(h[1]) + bf2f(l[1]),
                   bf2f(h[2]) + bf2f(l[2]), bf2f(h[3]) + bf2f(l[3])};
}
__device__ __forceinline__ float sigm(float x) { return 1.f / (1.f + expf(-x)); }

// ---------------------------------------------------------------------------
// GEMM descriptor: C = op(A @ B^T + bias); A (M,K) split bf16; B (N,K) split.
// ---------------------------------------------------------------------------
struct GD {
    const short *Ah, *Al, *Bh, *Bl;
    const float *bias;
    short *Ch, *Cl;
    int M, N, K, gx, nblk, relu;
};

// ---------------------------------------------------------------------------
// bf16-split MFMA GEMM with prefetch double-buffer (T3-minimum schedule).
//  BKL=32: 256 thr (4 waves 2x2), 64KB LDS, 2 blocks/CU   (G1, G9)
//  BKL=64: 512 thr (8 waves 4x2), 128KB LDS, 1 block/CU   (small GEMMs)
//  MODE 0: (pair-batched) split-store, runtime relu
//  MODE 2: G1 — video rows -> weighted u atomics; button rows -> relu store
//  MODE 3: G9 — relu -> wj2 dot -> LG atomics
// ---------------------------------------------------------------------------
template<int MODE, int BKL>
__global__ __launch_bounds__((BKL == 64 ? 512 : 256), 2) void mgemm3(
    GD d0, GD d1,
    const float* __restrict__ wt, float* __restrict__ uacc,
    const float* __restrict__ wj2, float* __restrict__ LG)
{
    constexpr int NTH = (BKL == 64) ? 512 : 256;
    constexpr int GPR = BKL / 8;          // 16B granules per LDS row
    constexpr int TSH = 128 * BKL;        // shorts per array per buffer
    constexpr int MF  = (BKL == 64) ? 2 : 4;
    constexpr int WMs = MF * 16;          // rows per wave
    __shared__ __align__(16) short lds[2 * 4 * TSH];

    const int tid = threadIdx.x;
    // bijective XCD-aware swizzle
    const int nwg = gridDim.x;
    const int orig = blockIdx.x;
    const int qq = nwg >> 3, r8 = nwg & 7, xcd = orig & 7, ridx = orig >> 3;
    const int swz = (xcd < r8 ? xcd * (qq + 1) : r8 * (qq + 1) + (xcd - r8) * qq) + ridx;

    GD d; int pid;
    if (swz < d0.nblk) { d = d0; pid = swz; } else { d = d1; pid = swz - d0.nblk; }
    const int bm = (pid / d.gx) * 128;
    const int bn = (pid % d.gx) * 128;

    const int wv = tid >> 6, l = tid & 63;
    const int fr = l & 15, fg = l >> 4;
    const int wr = wv >> 1, wc = wv & 1;

    f32x4 acc[MF][4];
#pragma unroll
    for (int m = 0; m < MF; ++m)
#pragma unroll
        for (int n = 0; n < 4; ++n) acc[m][n] = (f32x4){0.f, 0.f, 0.f, 0.f};

    auto stage = [&](int buf, int k0) {
        short* base = &lds[buf * 4 * TSH];
#pragma unroll
        for (int i = 0; i < (128 * GPR) / NTH; ++i) {
            int g = i * NTH + tid;
            int row = g / GPR, c = g % GPR;
            int cs = (BKL == 32) ? (c ^ ((row >> 1) & 3)) : (c ^ (row & 7));
            int ga = bm + row; if (ga > d.M - 1) ga = d.M - 1;
            size_t ao = (size_t)ga * d.K + k0 + cs * 8;
            size_t bo = (size_t)(bn + row) * d.K + k0 + cs * 8;
            gload16(d.Ah + ao, base + 0 * TSH + g * 8);
            gload16(d.Al + ao, base + 1 * TSH + g * 8);
            gload16(d.Bh + bo, base + 2 * TSH + g * 8);
            gload16(d.Bl + bo, base + 3 * TSH + g * 8);
        }
    };
    auto compute = [&](int buf) {
        const short* base = &lds[buf * 4 * TSH];
#pragma unroll
        for (int s = 0; s < BKL / 32; ++s) {
            s8v ah[MF], al[MF];
#pragma unroll
            for (int m = 0; m < MF; ++m) {
                int row = wr * WMs + m * 16 + fr;
                int sw = (BKL == 32) ? ((row >> 1) & 3) : (row & 7);
                int off = row * BKL + (((s << 2) + fg) ^ sw) * 8;
                ah[m] = *(const s8v*)&base[0 * TSH + off];
                al[m] = *(const s8v*)&base[1 * TSH + off];
            }
#pragma unroll
            for (int n = 0; n < 4; ++n) {
                int col = wc * 64 + n * 16 + fr;
                int sw = (BKL == 32) ? ((col >> 1) & 3) : (col & 7);
                int off = col * BKL + (((s << 2) + fg) ^ sw) * 8;
                s8v bh = *(const s8v*)&base[2 * TSH + off];
                s8v bl = *(const s8v*)&base[3 * TSH + off];
#pragma unroll
                for (int m = 0; m < MF; ++m) {
                    f32x4 c = acc[m][n];
                    c = __builtin_amdgcn_mfma_f32_16x16x32_bf16(al[m], bh, c, 0, 0, 0);
                    c = __builtin_amdgcn_mfma_f32_16x16x32_bf16(ah[m], bl, c, 0, 0, 0);
                    c = __builtin_amdgcn_mfma_f32_16x16x32_bf16(ah[m], bh, c, 0, 0, 0);
                    acc[m][n] = c;
                }
            }
        }
    };

    // prologue + prefetch-pipelined K loop (one barrier per step)
    stage(0, 0);
    __syncthreads();
    const int nk = d.K / BKL;
    int cur = 0;
    for (int t = 0; t < nk; ++t) {
        if (t + 1 < nk) stage(cur ^ 1, (t + 1) * BKL);
        compute(cur);
        __syncthreads();
        cur ^= 1;
    }

    // ---------------- epilogues ----------------
    if (MODE == 2 && bm < 16384) {
        float wtv[MF][4];
#pragma unroll
        for (int m = 0; m < MF; ++m)
#pragma unroll
            for (int r = 0; r < 4; ++r)
                wtv[m][r] = wt[bm + wr * WMs + m * 16 + fg * 4 + r];
#pragma unroll
        for (int n = 0; n < 4; ++n) {
            int gcol = bn + wc * 64 + n * 16 + fr;
            float bv = d.bias[gcol];
            float s = 0.f;
#pragma unroll
            for (int m = 0; m < MF; ++m)
#pragma unroll
                for (int r = 0; r < 4; ++r)
                    s += fmaxf(acc[m][n][r] + bv, 0.f) * wtv[m][r];
            s += __shfl_xor(s, 16);
            s += __shfl_xor(s, 32);
            if (fg == 0) atomicAdd(&uacc[gcol], s);
        }
        return;
    }
    if (MODE == 3) {
#pragma unroll
        for (int m = 0; m < MF; ++m) {
            float sv[4] = {0.f, 0.f, 0.f, 0.f};
#pragma unroll
            for (int n = 0; n < 4; ++n) {
                int gcol = bn + wc * 64 + n * 16 + fr;
                float bv = d.bias[gcol], w2 = wj2[gcol];
#pragma unroll
                for (int r = 0; r < 4; ++r)
                    sv[r] += fmaxf(acc[m][n][r] + bv, 0.f) * w2;
            }
#pragma unroll
            for (int r = 0; r < 4; ++r) {
                float v = sv[r];
                v += __shfl_xor(v, 1); v += __shfl_xor(v, 2);
                v += __shfl_xor(v, 4); v += __shfl_xor(v, 8);
                int gm = bm + wr * WMs + m * 16 + fg * 4 + r;
                if (fr == 0 && gm < d.M) atomicAdd(&LG[gm], v);
            }
        }
        return;
    }
    {
        const int rowoff = (MODE == 2) ? 16384 : 0;
#pragma unroll
        for (int n = 0; n < 4; ++n) {
            int gcol = bn + wc * 64 + n * 16 + fr;
            float bv = d.bias[gcol];
#pragma unroll
            for (int m = 0; m < MF; ++m) {
                int rbase = bm + wr * WMs + m * 16 + fg * 4;
#pragma unroll
                for (int r = 0; r < 4; ++r) {
                    int gm = rbase + r;
                    if (gm < d.M) {
                        float v = acc[m][n][r] + bv;
                        if (d.relu || MODE == 2) v = fmaxf(v, 0.f);
                        short hh, ll; split_rn(v, hh, ll);
                        size_t o = (size_t)(gm - rowoff) * d.N + gcol;
                        d.Ch[o] = hh; d.Cl[o] = ll;
                    }
                }
            }
        }
    }
}

// ---------------------------------------------------------------------------
// weight prep (transpose+split or plain split), one launch for all 9
// ---------------------------------------------------------------------------
struct PrepArgs {
    const float* src[9];
    short* dh[9]; short* dl[9];
    int K[9], N[9], tr[9];
};
__global__ __launch_bounds__(256) void prep_weights(PrepArgs a)
{
    const int wi = blockIdx.y;
    const float* src = a.src[wi];
    short* dh = a.dh[wi]; short* dl = a.dl[wi];
    const int K = a.K[wi], N = a.N[wi];
    __shared__ float t[32][33];
    if (a.tr[wi]) {
        int nb = N >> 5, kb = K >> 5;
        if ((int)blockIdx.x >= nb * kb) return;
        int tx = threadIdx.x & 31, ty = threadIdx.x >> 5;
        int n0 = ((int)blockIdx.x % nb) << 5, k0 = ((int)blockIdx.x / nb) << 5;
#pragma unroll
        for (int i = 0; i < 4; ++i)
            t[ty + 8 * i][tx] = src[(size_t)(k0 + ty + 8 * i) * N + n0 + tx];
        __syncthreads();
#pragma unroll
        for (int i = 0; i < 4; ++i) {
            int n = n0 + ty + 8 * i, k = k0 + tx;
            short h, l; split_rn(t[tx][ty + 8 * i], h, l);
            dh[(size_t)n * K + k] = h;
            dl[(size_t)n * K + k] = l;
        }
    } else {
        int total = K * N;
        int i0 = ((int)blockIdx.x * 256 + (int)threadIdx.x) * 4;
        if (i0 < total) {
            float4 v = *(const float4*)(src + i0);
            float vv[4] = {v.x, v.y, v.z, v.w};
#pragma unroll
            for (int e = 0; e < 4; ++e) {
                short h, l; split_rn(vv[e], h, l);
                dh[i0 + e] = h; dl[i0 + e] = l;
            }
        }
    }
}

__global__ __launch_bounds__(256) void asplit_vb(const float* __restrict__ video,
                                                 const float* __restrict__ btns,
                                                 short* __restrict__ h,
                                                 short* __restrict__ l)
{
    const size_t vtotal = (size_t)16384 * VD;
    const size_t total = (size_t)MVB * VD;
    for (size_t i = ((size_t)blockIdx.x * 256 + threadIdx.x) * 4; i < total;
         i += (size_t)gridDim.x * 1024) {
        const float* s = (i < vtotal) ? video + i : btns + (i - vtotal);
        float4 v = *(const float4*)s;
        float vv[4] = {v.x, v.y, v.z, v.w};
#pragma unroll
        for (int e = 0; e < 4; ++e) {
            short hh, ll; split_rn(vv[e], hh, ll);
            h[i + e] = hh; l[i + e] = ll;
        }
    }
}

// prolog: paragraph softmax, zero u, split state0 -> ASC row0, LG = bj2
__global__ __launch_bounds__(256) void prolog(const float* __restrict__ ps,
                                              float* __restrict__ sc,
                                              float* __restrict__ u,
                                              const float* __restrict__ state0,
                                              short* __restrict__ ASCh,
                                              short* __restrict__ ASCl,
                                              const float* __restrict__ bj2,
                                              float* __restrict__ LG)
{
    int b = blockIdx.x, tid = threadIdx.x;
    if (b == 0) {
        if (tid < 64) {
            float x = ps[tid];
            float m = x;
            for (int off = 32; off; off >>= 1) m = fmaxf(m, __shfl_xor(m, off));
            float e = expf(x - m);
            float s = e;
            for (int off = 32; off; off >>= 1) s += __shfl_xor(s, off);
            sc[tid] = e / s;
        }
    } else if (b == 1) {
#pragma unroll
        for (int i = 0; i < 4; ++i) u[tid + i * 256] = 0.f;
    } else if (b == 2) {
#pragma unroll
        for (int i = 0; i < 2; ++i) {
            int c = tid + i * 256;
            short h, l; split_rn(state0[c], h, l);
            ASCh[c] = h; ASCl[c] = l;
        }
    } else {
        int i = (b - 3) * 256 + tid;
        if (i < NCAND) LG[i] = bj2[0];
    }
}

__global__ __launch_bounds__(256) void wt_kernel(const int* __restrict__ ts,
                                                 const float* __restrict__ sc,
                                                 float* __restrict__ wt)
{
    __shared__ int ss[64], se[64];
    __shared__ float sw[64];
    int tid = threadIdx.x;
    if (tid < 64) {
        int s = ts[2 * tid];
        int e = ts[2 * tid + 1];
        if (e < s + 1) e = s + 1;
        ss[tid] = s; se[tid] = e;
        sw[tid] = sc[tid] / (float)(e - s);
    }
    __syncthreads();
    int t = blockIdx.x * 256 + tid;
    if (t < T_FRAMES) {
        float w = 0.f;
#pragma unroll
        for (int p = 0; p < 64; ++p)
            if (t >= ss[p] && t < se[p]) w += sw[p];
        wt[t] = w;
    }
}

// bias2[j] = bp1[j] + sum_i vseg[i]*wp1[i][j] + sum_i tseg[i]*wp1[256+i][j]
// vseg/tseg computed block-redundantly in LDS (subsumes videoseg+textseg).
__global__ __launch_bounds__(256) void mkbias2(const float* __restrict__ u,
                                               const float* __restrict__ wv2,
                                               const float* __restrict__ bv2,
                                               const float* __restrict__ sc,
                                               const short* __restrict__ T2h,
                                               const short* __restrict__ T2l,
                                               const float* __restrict__ bp1,
                                               const float* __restrict__ wp1,
                                               float* __restrict__ bias2)
{
    __shared__ float vs[256], ts[256];
    int tid = threadIdx.x;
    float a = 0.f;
    for (int p = 0; p < 64; ++p) {
        size_t o = (size_t)p * TO + tid;
        a = fmaf(sc[p], bf2f(T2h[o]) + bf2f(T2l[o]), a);
    }
    ts[tid] = a;
    float b = bv2[tid];
    for (int i = 0; i < VD; ++i)
        b = fmaf(u[i], wv2[(size_t)i * VO + tid], b);
    vs[tid] = b;
    __syncthreads();
    int j = blockIdx.x * 256 + tid;      // 4 blocks -> 1024 cols
    float acc = bp1[j];
    for (int i = 0; i < 256; ++i) acc = fmaf(vs[i], wp1[(size_t)i * 1024 + j], acc);
    for (int i = 0; i < 256; ++i) acc = fmaf(ts[i], wp1[(size_t)(256 + i) * 1024 + j], acc);
    bias2[j] = acc;
}

// stack [para; question; a_texts] -> split Xt (2113 x 768)
__global__ __launch_bounds__(256) void copy_xt_split(const float* __restrict__ para,
                                                     const float* __restrict__ question,
                                                     const float* __restrict__ atexts,
                                                     short* __restrict__ Xh,
                                                     short* __restrict__ Xl)
{
    size_t total = (size_t)NTXT * TD;
    for (size_t id = ((size_t)blockIdx.x * 256 + threadIdx.x) * 4; id < total;
         id += (size_t)gridDim.x * 1024) {
        int r = (int)(id / TD);
        int c = (int)(id - (size_t)r * TD);
        const float* s;
        if (r < 64)       s = para + (size_t)r * TD + c;
        else if (r == 64) s = question + c;
        else              s = atexts + (size_t)(r - 65) * TD + c;
        float4 v = *(const float4*)s;
        float vv[4] = {v.x, v.y, v.z, v.w};
#pragma unroll
        for (int e = 0; e < 4; ++e) {
            short h, l; split_rn(vv[e], h, l);
            Xh[id + e] = h; Xl[id + e] = l;
        }
    }
}

// Xp row r = [q + T2[65+r] | btn[r]]  (2048 x 512), 4-wide
__global__ __launch_bounds__(256) void xp_build_split(const short* __restrict__ T2h,
                                                      const short* __restrict__ T2l,
                                                      const short* __restrict__ btnh,
                                                      const short* __restrict__ btnl,
                                                      short* __restrict__ Xh,
                                                      short* __restrict__ Xl)
{
    int idx = blockIdx.x * 256 + threadIdx.x;    // 262144 total
    int r = idx >> 7;
    int c = (idx & 127) << 2;
    s4v h, l;
    if (c < 256) {
        size_t o1 = (size_t)64 * TO + c;
        size_t o2 = (size_t)(65 + r) * TO + c;
        s4v h1 = *(const s4v*)(T2h + o1), l1 = *(const s4v*)(T2l + o1);
        s4v h2 = *(const s4v*)(T2h + o2), l2 = *(const s4v*)(T2l + o2);
#pragma unroll
        for (int e = 0; e < 4; ++e) {
            float v = (bf2f(h1[e]) + bf2f(l1[e])) + (bf2f(h2[e]) + bf2f(l2[e]));
            short hh, ll; split_rn(v, hh, ll);
            h[e] = hh; l[e] = ll;
        }
    } else {
        size_t o = (size_t)r * VO + (c - 256);
        h = *(const s4v*)(btnh + o);
        l = *(const s4v*)(btnl + o);
    }
    size_t out = (size_t)r * 512 + c;
    *(s4v*)(Xh + out) = h;
    *(s4v*)(Xl + out) = l;
}

// GRU gate fusion, 4-wide vectorized
__global__ __launch_bounds__(256) void hn_build(const short* __restrict__ GIh,
                                                const short* __restrict__ GIl,
                                                const short* __restrict__ GHh,
                                                const short* __restrict__ GHl,
                                                const short* __restrict__ ASCh,
                                                const short* __restrict__ ASCl,
                                                short* __restrict__ HNh,
                                                short* __restrict__ HNl)
{
    const int total = NCAND * 128;
    for (int gid = blockIdx.x * 256 + threadIdx.x; gid < total;
         gid += gridDim.x * 256) {
        int r = gid >> 7;
        int c = (gid & 127) << 2;
        int crow, girow;
        if (r < 16) { crow = 0; girow = r; }
        else {
            int rr = r - 16;
            int k  = 1 + (rr >> 8);
            int rem = rr & 255;
            int ci = rem >> 4;
            int aa = rem & 15;
            crow = 1 + (k - 1) * 16 + ci;
            girow = k * 16 + aa;
        }
        size_t gi0 = (size_t)girow * 1536 + c;
        size_t gh0 = (size_t)crow * 1536 + c;
        f32x4 ir = ld4s(GIh, GIl, gi0);
        f32x4 iz = ld4s(GIh, GIl, gi0 + 512);
        f32x4 in = ld4s(GIh, GIl, gi0 + 1024);
        f32x4 hr = ld4s(GHh, GHl, gh0);
        f32x4 hz = ld4s(GHh, GHl, gh0 + 512);
        f32x4 hn = ld4s(GHh, GHl, gh0 + 1024);
        f32x4 h  = ld4s(ASCh, ASCl, (size_t)crow * HH + c);
        s4v oh, ol;
#pragma unroll
        for (int e = 0; e < 4; ++e) {
            float rg = sigm(ir[e] + hr[e]);
            float z  = sigm(iz[e] + hz[e]);
            float n  = tanhf(in[e] + rg * hn[e]);
            float v  = (1.f - z) * n + z * h[e];
            short hh, ll; split_rn(v, hh, ll);
            oh[e] = hh; ol[e] = ll;
        }
        size_t out = (size_t)r * HH + c;
        *(s4v*)(HNh + out) = oh;
        *(s4v*)(HNl + out) = ol;
    }
}

// per-group argmax (first-max), wave per group
__global__ __launch_bounds__(256) void argmax16(const float* __restrict__ LG,
                                                int* __restrict__ idx)
{
    int g = blockIdx.x * 4 + (threadIdx.x >> 6);
    if (g >= NGRP) return;
    int lane = threadIdx.x & 63;
    float v = (lane < 16) ? LG[g * 16 + lane] : -INFINITY;
    int bi = (lane < 16) ? lane : 16;
    for (int off = 8; off >= 1; off >>= 1) {
        float ov = __shfl_xor(v, off);
        int   oi = __shfl_xor(bi, off);
        if (ov > v || (ov == v && oi < bi)) { v = ov; bi = oi; }
    }
    if (lane == 0) idx[g] = bi;
}

// sequential pointer-chase through precomputed argmax table (1 wave)
__global__ void chase2(const float* __restrict__ LG, const int* __restrict__ idx,
                       float* __restrict__ out)
{
    int lane = threadIdx.x;
    int g = 0;
    for (int k = 0; k < S_N; ++k) {
        if (lane < 16) out[k * 16 + lane] = LG[g * 16 + lane];
        int ci = idx[g];
        g = 1 + k * 16 + ci;
    }
}

// ---------------------------------------------------------------------------
extern "C" void kernel_launch(void* const* d_in, const int* in_sizes, int n_in,
                              void* d_out, int out_size, void* d_ws, size_t ws_size,
                              hipStream_t stream)
{
    const float* video      = (const float*)d_in[0];
    const float* para       = (const float*)d_in[1];
    const float* question   = (const float*)d_in[2];
    const float* paras_scr  = (const float*)d_in[3];
    const float* a_texts    = (const float*)d_in[4];
    const float* a_buttons  = (const float*)d_in[5];
    const int*   timestamps = (const int*)d_in[6];
    const float* wv1 = (const float*)d_in[7];
    const float* bv1 = (const float*)d_in[8];
    const float* wv2 = (const float*)d_in[9];
    const float* bv2 = (const float*)d_in[10];
    const float* wt1 = (const float*)d_in[11];
    const float* bt1 = (const float*)d_in[12];
    const float* wt2 = (const float*)d_in[13];
    const float* bt2 = (const float*)d_in[14];
    const float* wp1 = (const float*)d_in[15];
    const float* bp1 = (const float*)d_in[16];
    const float* wp2 = (const float*)d_in[17];
    const float* bp2 = (const float*)d_in[18];
    const float* w_ih = (const float*)d_in[19];
    const float* b_ih = (const float*)d_in[20];
    const float* w_hh = (const float*)d_in[21];
    const float* b_hh = (const float*)d_in[22];
    const float* wj1 = (const float*)d_in[23];
    const float* bj1 = (const float*)d_in[24];
    const float* wj2 = (const float*)d_in[25];
    const float* bj2 = (const float*)d_in[26];
    const float* state0 = (const float*)d_in[27];

    char* wsb = (char*)d_ws;
    size_t off = 0;
    auto alloc = [&](size_t bytes) -> char* {
        size_t o = (off + 255) & ~(size_t)255;
        off = o + bytes;
        return wsb + o;
    };
    auto allocF = [&](size_t n) -> float* { return (float*)alloc(n * 4); };
    auto allocS = [&](size_t n) -> short* { return (short*)alloc(n * 2); };
    auto allocI = [&](size_t n) -> int*   { return (int*)alloc(n * 4); };

    float* sc    = allocF(64);
    float* wtb   = allocF(T_FRAMES);
    float* u     = allocF(VD);
    float* bias2 = allocF(1024);
    float* LG    = allocF(NCAND);
    int*   amx   = allocI(NGRP);

    short* Avbh = allocS((size_t)MVB * VD);       // later reused as HNh
    short* Avbl = allocS((size_t)MVB * VD);       // later reused as HNl
    short* H1bh = allocS((size_t)2048 * VD);
    short* H1bl = allocS((size_t)2048 * VD);
    short* Xth  = allocS((size_t)NTXT * TD);
    short* Xtl  = allocS((size_t)NTXT * TD);
    short* T1h  = allocS((size_t)NTXT * TD);
    short* T1l  = allocS((size_t)NTXT * TD);
    short* T2h  = allocS((size_t)NTXT * TO);
    short* T2l  = allocS((size_t)NTXT * TO);
    short* btnh = allocS((size_t)2048 * VO);
    short* btnl = allocS((size_t)2048 * VO);
    short* Xph  = allocS((size_t)2048 * 512);
    short* Xpl  = allocS((size_t)2048 * 512);
    short* P1h  = allocS((size_t)2048 * 1024);
    short* P1l  = allocS((size_t)2048 * 1024);
    short* ASCh = allocS((size_t)NASC * HH);
    short* ASCl = allocS((size_t)NASC * HH);
    short* GIh  = allocS((size_t)2048 * 1536);
    short* GIl  = allocS((size_t)2048 * 1536);
    short* GHh  = allocS((size_t)NASC * 1536);
    short* GHl  = allocS((size_t)NASC * 1536);
    short* IPh  = ASCh + HH;                      // IP = ASC rows 1..2048
    short* IPl  = ASCl + HH;
    short* HNh  = Avbh;                           // Avb dead after G1
    short* HNl  = Avbl;

    short* wv1Th = allocS((size_t)VD * VD);    short* wv1Tl = allocS((size_t)VD * VD);
    short* wt1Th = allocS((size_t)TD * TD);    short* wt1Tl = allocS((size_t)TD * TD);
    short* wt2Th = allocS((size_t)TO * TD);    short* wt2Tl = allocS((size_t)TO * TD);
    short* wv2Th = allocS((size_t)VO * VD);    short* wv2Tl = allocS((size_t)VO * VD);
    short* wp1Th = allocS((size_t)1024 * 512); short* wp1Tl = allocS((size_t)1024 * 512);
    short* wp2Th = allocS((size_t)HH * 1024);  short* wp2Tl = allocS((size_t)HH * 1024);
    short* wj1Th = allocS((size_t)HH * HH);    short* wj1Tl = allocS((size_t)HH * HH);
    short* wihSh = allocS((size_t)1536 * HH);  short* wihSl = allocS((size_t)1536 * HH);
    short* whhSh = allocS((size_t)1536 * HH);  short* whhSl = allocS((size_t)1536 * HH);

    GD gE; gE.Ah = gE.Al = gE.Bh = gE.Bl = nullptr; gE.bias = nullptr;
    gE.Ch = gE.Cl = nullptr; gE.M = gE.N = gE.K = gE.gx = gE.nblk = gE.relu = 0;

    // 1. prolog
    prolog<<<131, 256, 0, stream>>>(paras_scr, sc, u, state0, ASCh, ASCl, bj2, LG);
    // 2. frame weights
    wt_kernel<<<T_FRAMES / 256, 256, 0, stream>>>(timestamps, sc, wtb);
    // 3. weight splits (wp1: only rows [512:1024) are GEMM'd; rest folds to bias2)
    {
        PrepArgs pa;
        const float* s[9] = {wv1, wt1, wt2, wv2, wp1 + (size_t)512 * 1024, wp2, wj1, w_ih, w_hh};
        short* dh[9] = {wv1Th, wt1Th, wt2Th, wv2Th, wp1Th, wp2Th, wj1Th, wihSh, whhSh};
        short* dl[9] = {wv1Tl, wt1Tl, wt2Tl, wv2Tl, wp1Tl, wp2Tl, wj1Tl, wihSl, whhSl};
        int K[9] = {VD, TD, TD, VD, 512, 1024, HH, HH, HH};
        int N[9] = {VD, TD, TO, VO, 1024, HH, HH, 1536, 1536};
        int tr[9] = {1, 1, 1, 1, 1, 1, 1, 0, 0};
        for (int i = 0; i < 9; ++i) {
            pa.src[i] = s[i]; pa.dh[i] = dh[i]; pa.dl[i] = dl[i];
            pa.K[i] = K[i]; pa.N[i] = N[i]; pa.tr[i] = tr[i];
        }
        prep_weights<<<dim3(1024, 9), 256, 0, stream>>>(pa);
    }
    // 4-5. activation splits
    asplit_vb<<<4608, 256, 0, stream>>>(video, a_buttons, Avbh, Avbl);
    copy_xt_split<<<1586, 256, 0, stream>>>(para, question, a_texts, Xth, Xtl);

    // G1: merged layer-1 (video rows -> u atomics, button rows -> H1b)
    {
        GD g1{Avbh, Avbl, wv1Th, wv1Tl, bv1, H1bh, H1bl, MVB, VD, VD, 8, 1152, 1};
        mgemm3<2, 32><<<1152, 256, 0, stream>>>(g1, gE, wtb, u, nullptr, nullptr);
    }
    // G2+G3 batched: btn GEMM + text layer-1
    {
        GD g2{H1bh, H1bl, wv2Th, wv2Tl, bv2, btnh, btnl, 2048, VO, VD, 2, 32, 0};
        GD g3{Xth, Xtl, wt1Th, wt1Tl, bt1, T1h, T1l, NTXT, TD, TD, 6, 102, 1};
        mgemm3<0, 64><<<134, 512, 0, stream>>>(g2, g3, nullptr, nullptr, nullptr, nullptr);
    }
    // G4: text layer-2
    {
        GD g4{T1h, T1l, wt2Th, wt2Tl, bt2, T2h, T2l, NTXT, TO, TD, 2, 34, 0};
        mgemm3<0, 64><<<34, 512, 0, stream>>>(g4, gE, nullptr, nullptr, nullptr, nullptr);
    }
    // bias2 = bp1 + [vseg|tseg] @ wp1[:512]  (subsumes videoseg/textseg)
    mkbias2<<<4, 256, 0, stream>>>(u, wv2, bv2, sc, T2h, T2l, bp1, wp1, bias2);
    // Xp = [qa | btn]
    xp_build_split<<<1024, 256, 0, stream>>>(T2h, T2l, btnh, btnl, Xph, Xpl);
    // G5/G6: pre-GRU MLP (G5 K shrunk to 512 via bias2 fold)
    {
        GD g5{Xph, Xpl, wp1Th, wp1Tl, bias2, P1h, P1l, 2048, 1024, 512, 8, 128, 1};
        mgemm3<0, 64><<<128, 512, 0, stream>>>(g5, gE, nullptr, nullptr, nullptr, nullptr);
    }
    {
        GD g6{P1h, P1l, wp2Th, wp2Tl, bp2, IPh, IPl, 2048, HH, 1024, 4, 64, 0};
        mgemm3<0, 64><<<64, 512, 0, stream>>>(g6, gE, nullptr, nullptr, nullptr, nullptr);
    }
    // G7+G8 batched: GRU gate GEMMs
    {
        GD g7{IPh, IPl, wihSh, wihSl, b_ih, GIh, GIl, 2048, 1536, HH, 12, 192, 0};
        GD g8{ASCh, ASCl, whhSh, whhSl, b_hh, GHh, GHl, NASC, 1536, HH, 12, 204, 0};
        mgemm3<0, 64><<<396, 512, 0, stream>>>(g7, g8, nullptr, nullptr, nullptr, nullptr);
    }
    // gate fusion
    hn_build<<<4096, 256, 0, stream>>>(GIh, GIl, GHh, GHl, ASCh, ASCl, HNh, HNl);
    // G9: judge MLP fused to logits
    {
        GD g9{HNh, HNl, wj1Th, wj1Tl, bj1, nullptr, nullptr, NCAND, HH, HH, 4, 1020, 0};
        mgemm3<3, 32><<<1020, 256, 0, stream>>>(g9, gE, nullptr, nullptr, wj2, LG);
    }
    // parallel argmax + short chase
    argmax16<<<(NGRP + 3) / 4, 256, 0, stream>>>(LG, amx);
    chase2<<<1, 64, 0, stream>>>(LG, amx, (float*)d_out);
}

// Round 5
// 570.987 us; speedup vs baseline: 3.7534x; 1.1505x over previous
//
#include <hip/hip_runtime.h>
#include <math.h>

#define T_FRAMES 16384
#define S_N   128
#define VD    1024
#define VO    256
#define TD    768
#define TO    256
#define HH    512
#define NTXT  2113            // 64 para + 1 question + 2048 a_texts
#define NCAND 32528           // 16 + 127*256 candidate rows
#define NGRP  2033            // NCAND / 16
#define NASC  2049            // state0 + 2048 inputs_pre rows
#define MVB   18432           // video 16384 + buttons 2048

typedef __attribute__((ext_vector_type(8))) short s8v;
typedef __attribute__((ext_vector_type(4))) short s4v;
typedef __attribute__((ext_vector_type(4))) float f32x4;

__device__ __forceinline__ float bf2f(short h) {
    return __builtin_bit_cast(float, ((unsigned)(unsigned short)h) << 16);
}
__device__ __forceinline__ void split_rn(float v, short& h, short& l) {
    unsigned u = __builtin_bit_cast(unsigned, v);
    unsigned short uh = (unsigned short)((u + 0x7fff + ((u >> 16) & 1)) >> 16);
    float lf = v - bf2f((short)uh);
    unsigned ul = __builtin_bit_cast(unsigned, lf);
    unsigned short us = (unsigned short)((ul + 0x7fff + ((ul >> 16) & 1)) >> 16);
    h = (short)uh; l = (short)us;
}
__device__ __forceinline__ void gload16(const void* g, void* l) {
    __builtin_amdgcn_global_load_lds(
        (const __attribute__((address_space(1))) unsigned int*)g,
        (__attribute__((address_space(3))) unsigned int*)l, 16, 0, 0);
}
__device__ __forceinline__ f32x4 ld4s(const short* __restrict__ H,
                                      const short* __restrict__ L, size_t o) {
    s4v h = *(const s4v*)(H + o);
    s4v l = *(const s4v*)(L + o);
    return (f32x4){bf2f(h[0]) + bf2f(l[0]), bf2f(h[1]) + bf2f(l[1]),
                   bf2f(h[2]) + bf2f(l[2]), bf2f(h[3]) + bf2f(l[3])};
}
__device__ __forceinline__ float sigm(float x) { return 1.f / (1.f + expf(-x)); }

// ---------------------------------------------------------------------------
// GEMM descriptor: C = op(A @ B^T + bias); A (M,K) split bf16; B (N,K) split.
// mode: 0 store, 1 relu-store, 2 G1 (video rows->u atomics, buttons relu-store
//       with row offset 16384), 3 G9 (relu -> wj2 dot -> LG atomics)
// ---------------------------------------------------------------------------
struct GD {
    const short *Ah, *Al, *Bh, *Bl;
    const float *bias;
    short *Ch, *Cl;
    int M, N, K, lda, ldb, gx, nblk, mode;
};

// ---------------------------------------------------------------------------
// bf16-split MFMA GEMM engine.
//  BKL=32: 256 thr (4 waves 2x2), single-buffered 32KB LDS -> many blocks/CU.
//          For large-grid GEMMs (TLP hides the barrier drain).
//  BKL=64: 512 thr (8 waves 4x2), double-buffered prefetch, 128KB LDS.
//          For thin latency-bound GEMMs (prefetch hides load latency).
// ---------------------------------------------------------------------------
template<int BKL>
__global__ __launch_bounds__((BKL == 64 ? 512 : 256), 2) void gemmk(
    GD d0, GD d1,
    const float* __restrict__ wt, float* __restrict__ uacc,
    const float* __restrict__ wj2, float* __restrict__ LG)
{
    constexpr int NTH  = (BKL == 64) ? 512 : 256;
    constexpr int GPR  = BKL / 8;          // 16B granules per LDS row
    constexpr int TSH  = 128 * BKL;        // shorts per array per buffer
    constexpr int MF   = (BKL == 64) ? 2 : 4;
    constexpr int WMs  = MF * 16;          // rows per wave
    constexpr int NBUF = (BKL == 64) ? 2 : 1;
    __shared__ __align__(16) short lds[NBUF * 4 * TSH];

    const int tid = threadIdx.x;
    // bijective XCD-aware swizzle
    const int nwg = gridDim.x;
    const int orig = blockIdx.x;
    const int qq = nwg >> 3, r8 = nwg & 7, xcd = orig & 7, ridx = orig >> 3;
    const int swz = (xcd < r8 ? xcd * (qq + 1) : r8 * (qq + 1) + (xcd - r8) * qq) + ridx;

    GD d; int pid;
    if (swz < d0.nblk) { d = d0; pid = swz; } else { d = d1; pid = swz - d0.nblk; }
    const int bm = (pid / d.gx) * 128;
    const int bn = (pid % d.gx) * 128;

    const int wv = tid >> 6, l = tid & 63;
    const int fr = l & 15, fg = l >> 4;
    const int wr = wv >> 1, wc = wv & 1;

    f32x4 acc[MF][4];
#pragma unroll
    for (int m = 0; m < MF; ++m)
#pragma unroll
        for (int n = 0; n < 4; ++n) acc[m][n] = (f32x4){0.f, 0.f, 0.f, 0.f};

    auto stage = [&](int buf, int k0) {
        short* base = &lds[buf * 4 * TSH];
#pragma unroll
        for (int i = 0; i < (128 * GPR) / NTH; ++i) {
            int g = i * NTH + tid;
            int row = g / GPR, c = g % GPR;
            int cs = (BKL == 32) ? (c ^ ((row >> 1) & 3)) : (c ^ (row & 7));
            int ga = bm + row; if (ga > d.M - 1) ga = d.M - 1;
            size_t ao = (size_t)ga * d.lda + k0 + cs * 8;
            size_t bo = (size_t)(bn + row) * d.ldb + k0 + cs * 8;
            gload16(d.Ah + ao, base + 0 * TSH + g * 8);
            gload16(d.Al + ao, base + 1 * TSH + g * 8);
            gload16(d.Bh + bo, base + 2 * TSH + g * 8);
            gload16(d.Bl + bo, base + 3 * TSH + g * 8);
        }
    };
    auto compute = [&](int buf) {
        const short* base = &lds[buf * 4 * TSH];
#pragma unroll
        for (int s = 0; s < BKL / 32; ++s) {
            s8v ah[MF], al[MF];
#pragma unroll
            for (int m = 0; m < MF; ++m) {
                int row = wr * WMs + m * 16 + fr;
                int sw = (BKL == 32) ? ((row >> 1) & 3) : (row & 7);
                int off = row * BKL + (((s << 2) + fg) ^ sw) * 8;
                ah[m] = *(const s8v*)&base[0 * TSH + off];
                al[m] = *(const s8v*)&base[1 * TSH + off];
            }
#pragma unroll
            for (int n = 0; n < 4; ++n) {
                int col = wc * 64 + n * 16 + fr;
                int sw = (BKL == 32) ? ((col >> 1) & 3) : (col & 7);
                int off = col * BKL + (((s << 2) + fg) ^ sw) * 8;
                s8v bh = *(const s8v*)&base[2 * TSH + off];
                s8v bl = *(const s8v*)&base[3 * TSH + off];
#pragma unroll
                for (int m = 0; m < MF; ++m) {
                    f32x4 c = acc[m][n];
                    c = __builtin_amdgcn_mfma_f32_16x16x32_bf16(al[m], bh, c, 0, 0, 0);
                    c = __builtin_amdgcn_mfma_f32_16x16x32_bf16(ah[m], bl, c, 0, 0, 0);
                    c = __builtin_amdgcn_mfma_f32_16x16x32_bf16(ah[m], bh, c, 0, 0, 0);
                    acc[m][n] = c;
                }
            }
        }
    };

    const int nk = d.K / BKL;
    if (NBUF == 1) {
        for (int t = 0; t < nk; ++t) {
            stage(0, t * BKL);
            __syncthreads();
            compute(0);
            __syncthreads();
        }
    } else {
        stage(0, 0);
        __syncthreads();
        int cur = 0;
        for (int t = 0; t < nk; ++t) {
            if (t + 1 < nk) stage(cur ^ 1, (t + 1) * BKL);
            compute(cur);
            __syncthreads();
            cur ^= 1;
        }
    }

    // ---------------- epilogues ----------------
    if (d.mode == 2 && bm < 16384) {
        float wtv[MF][4];
#pragma unroll
        for (int m = 0; m < MF; ++m)
#pragma unroll
            for (int r = 0; r < 4; ++r)
                wtv[m][r] = wt[bm + wr * WMs + m * 16 + fg * 4 + r];
#pragma unroll
        for (int n = 0; n < 4; ++n) {
            int gcol = bn + wc * 64 + n * 16 + fr;
            float bv = d.bias[gcol];
            float s = 0.f;
#pragma unroll
            for (int m = 0; m < MF; ++m)
#pragma unroll
                for (int r = 0; r < 4; ++r)
                    s += fmaxf(acc[m][n][r] + bv, 0.f) * wtv[m][r];
            s += __shfl_xor(s, 16);
            s += __shfl_xor(s, 32);
            if (fg == 0) atomicAdd(&uacc[gcol], s);
        }
        return;
    }
    if (d.mode == 3) {
#pragma unroll
        for (int m = 0; m < MF; ++m) {
            float sv[4] = {0.f, 0.f, 0.f, 0.f};
#pragma unroll
            for (int n = 0; n < 4; ++n) {
                int gcol = bn + wc * 64 + n * 16 + fr;
                float bv = d.bias[gcol], w2 = wj2[gcol];
#pragma unroll
                for (int r = 0; r < 4; ++r)
                    sv[r] += fmaxf(acc[m][n][r] + bv, 0.f) * w2;
            }
#pragma unroll
            for (int r = 0; r < 4; ++r) {
                float v = sv[r];
                v += __shfl_xor(v, 1); v += __shfl_xor(v, 2);
                v += __shfl_xor(v, 4); v += __shfl_xor(v, 8);
                int gm = bm + wr * WMs + m * 16 + fg * 4 + r;
                if (fr == 0 && gm < d.M) atomicAdd(&LG[gm], v);
            }
        }
        return;
    }
    {
        const int rowoff = (d.mode == 2) ? 16384 : 0;
        const bool dorelu = (d.mode >= 1);
#pragma unroll
        for (int n = 0; n < 4; ++n) {
            int gcol = bn + wc * 64 + n * 16 + fr;
            float bv = d.bias[gcol];
#pragma unroll
            for (int m = 0; m < MF; ++m) {
                int rbase = bm + wr * WMs + m * 16 + fg * 4;
#pragma unroll
                for (int r = 0; r < 4; ++r) {
                    int gm = rbase + r;
                    if (gm < d.M) {
                        float v = acc[m][n][r] + bv;
                        if (dorelu) v = fmaxf(v, 0.f);
                        short hh, ll; split_rn(v, hh, ll);
                        size_t o = (size_t)(gm - rowoff) * d.N + gcol;
                        d.Ch[o] = hh; d.Cl[o] = ll;
                    }
                }
            }
        }
    }
}

// ---------------------------------------------------------------------------
// weight prep (transpose+split or plain split), one launch for all 9
// ---------------------------------------------------------------------------
struct PrepArgs {
    const float* src[9];
    short* dh[9]; short* dl[9];
    int K[9], N[9], tr[9];
};
__global__ __launch_bounds__(256) void prep_weights(PrepArgs a)
{
    const int wi = blockIdx.y;
    const float* src = a.src[wi];
    short* dh = a.dh[wi]; short* dl = a.dl[wi];
    const int K = a.K[wi], N = a.N[wi];
    __shared__ float t[32][33];
    if (a.tr[wi]) {
        int nb = N >> 5, kb = K >> 5;
        if ((int)blockIdx.x >= nb * kb) return;
        int tx = threadIdx.x & 31, ty = threadIdx.x >> 5;
        int n0 = ((int)blockIdx.x % nb) << 5, k0 = ((int)blockIdx.x / nb) << 5;
#pragma unroll
        for (int i = 0; i < 4; ++i)
            t[ty + 8 * i][tx] = src[(size_t)(k0 + ty + 8 * i) * N + n0 + tx];
        __syncthreads();
#pragma unroll
        for (int i = 0; i < 4; ++i) {
            int n = n0 + ty + 8 * i, k = k0 + tx;
            short h, l; split_rn(t[tx][ty + 8 * i], h, l);
            dh[(size_t)n * K + k] = h;
            dl[(size_t)n * K + k] = l;
        }
    } else {
        int total = K * N;
        int i0 = ((int)blockIdx.x * 256 + (int)threadIdx.x) * 4;
        if (i0 < total) {
            float4 v = *(const float4*)(src + i0);
            float vv[4] = {v.x, v.y, v.z, v.w};
#pragma unroll
            for (int e = 0; e < 4; ++e) {
                short h, l; split_rn(vv[e], h, l);
                dh[i0 + e] = h; dl[i0 + e] = l;
            }
        }
    }
}

__global__ __launch_bounds__(256) void asplit_vb(const float* __restrict__ video,
                                                 const float* __restrict__ btns,
                                                 short* __restrict__ h,
                                                 short* __restrict__ l)
{
    const size_t vtotal = (size_t)16384 * VD;
    const size_t total = (size_t)MVB * VD;
    for (size_t i = ((size_t)blockIdx.x * 256 + threadIdx.x) * 4; i < total;
         i += (size_t)gridDim.x * 1024) {
        const float* s = (i < vtotal) ? video + i : btns + (i - vtotal);
        float4 v = *(const float4*)s;
        float vv[4] = {v.x, v.y, v.z, v.w};
#pragma unroll
        for (int e = 0; e < 4; ++e) {
            short hh, ll; split_rn(vv[e], hh, ll);
            h[i + e] = hh; l[i + e] = ll;
        }
    }
}

// prolog: paragraph softmax, zero u, split state0 -> ASC row0, LG = bj2
__global__ __launch_bounds__(256) void prolog(const float* __restrict__ ps,
                                              float* __restrict__ sc,
                                              float* __restrict__ u,
                                              const float* __restrict__ state0,
                                              short* __restrict__ ASCh,
                                              short* __restrict__ ASCl,
                                              const float* __restrict__ bj2,
                                              float* __restrict__ LG)
{
    int b = blockIdx.x, tid = threadIdx.x;
    if (b == 0) {
        if (tid < 64) {
            float x = ps[tid];
            float m = x;
            for (int off = 32; off; off >>= 1) m = fmaxf(m, __shfl_xor(m, off));
            float e = expf(x - m);
            float s = e;
            for (int off = 32; off; off >>= 1) s += __shfl_xor(s, off);
            sc[tid] = e / s;
        }
    } else if (b == 1) {
#pragma unroll
        for (int i = 0; i < 4; ++i) u[tid + i * 256] = 0.f;
    } else if (b == 2) {
#pragma unroll
        for (int i = 0; i < 2; ++i) {
            int c = tid + i * 256;
            short h, l; split_rn(state0[c], h, l);
            ASCh[c] = h; ASCl[c] = l;
        }
    } else {
        int i = (b - 3) * 256 + tid;
        if (i < NCAND) LG[i] = bj2[0];
    }
}

__global__ __launch_bounds__(256) void wt_kernel(const int* __restrict__ ts,
                                                 const float* __restrict__ sc,
                                                 float* __restrict__ wt)
{
    __shared__ int ss[64], se[64];
    __shared__ float sw[64];
    int tid = threadIdx.x;
    if (tid < 64) {
        int s = ts[2 * tid];
        int e = ts[2 * tid + 1];
        if (e < s + 1) e = s + 1;
        ss[tid] = s; se[tid] = e;
        sw[tid] = sc[tid] / (float)(e - s);
    }
    __syncthreads();
    int t = blockIdx.x * 256 + tid;
    if (t < T_FRAMES) {
        float w = 0.f;
#pragma unroll
        for (int p = 0; p < 64; ++p)
            if (t >= ss[p] && t < se[p]) w += sw[p];
        wt[t] = w;
    }
}

// segc[0:256) = vseg = u@wv2+bv2 (wave-dot over split wv2T);
// segc[256:512) = tseg = sc@T2[0:64]
__global__ __launch_bounds__(256) void mkseg(const float* __restrict__ u,
                                             const short* __restrict__ wh,
                                             const short* __restrict__ wl,
                                             const float* __restrict__ bv2,
                                             const float* __restrict__ sc,
                                             const short* __restrict__ T2h,
                                             const short* __restrict__ T2l,
                                             float* __restrict__ segc)
{
    int b = blockIdx.x;
    if (b < 64) {
        int j = b * 4 + (threadIdx.x >> 6);
        int lane = threadIdx.x & 63;
        const s8v* ph = (const s8v*)(wh + (size_t)j * VD + lane * 16);
        const s8v* pl = (const s8v*)(wl + (size_t)j * VD + lane * 16);
        const float4* pu = (const float4*)(u + lane * 16);
        float acc = 0.f;
#pragma unroll
        for (int qq = 0; qq < 2; ++qq) {
            s8v h = ph[qq], l = pl[qq];
            float4 u0 = pu[qq * 2], u1 = pu[qq * 2 + 1];
            float uu[8] = {u0.x, u0.y, u0.z, u0.w, u1.x, u1.y, u1.z, u1.w};
#pragma unroll
            for (int e = 0; e < 8; ++e)
                acc = fmaf(uu[e], bf2f(h[e]) + bf2f(l[e]), acc);
        }
        for (int off = 32; off; off >>= 1) acc += __shfl_xor(acc, off);
        if (lane == 0) segc[j] = acc + bv2[j];
    } else {
        int j = threadIdx.x;
        float acc = 0.f;
        for (int p = 0; p < 64; ++p) {
            size_t o = (size_t)p * TO + j;
            acc = fmaf(sc[p], bf2f(T2h[o]) + bf2f(T2l[o]), acc);
        }
        segc[256 + j] = acc;
    }
}

// bias2[j] = bp1[j] + sum_{i<512} segc[i] * wp1[i][j]   (wave per j, wp1T split)
__global__ __launch_bounds__(256) void bias2k(const float* __restrict__ segc,
                                              const short* __restrict__ wp1Th,
                                              const short* __restrict__ wp1Tl,
                                              const float* __restrict__ bp1,
                                              float* __restrict__ bias2)
{
    int j = blockIdx.x * 4 + (threadIdx.x >> 6);
    int lane = threadIdx.x & 63;
    s8v h = *(const s8v*)(wp1Th + (size_t)j * 1024 + lane * 8);
    s8v l = *(const s8v*)(wp1Tl + (size_t)j * 1024 + lane * 8);
    const float4* ps = (const float4*)(segc + lane * 8);
    float4 s0 = ps[0], s1 = ps[1];
    float sv[8] = {s0.x, s0.y, s0.z, s0.w, s1.x, s1.y, s1.z, s1.w};
    float acc = 0.f;
#pragma unroll
    for (int e = 0; e < 8; ++e)
        acc = fmaf(sv[e], bf2f(h[e]) + bf2f(l[e]), acc);
    for (int off = 32; off; off >>= 1) acc += __shfl_xor(acc, off);
    if (lane == 0) bias2[j] = acc + bp1[j];
}

// stack [para; question; a_texts] -> split Xt (2113 x 768)
__global__ __launch_bounds__(256) void copy_xt_split(const float* __restrict__ para,
                                                     const float* __restrict__ question,
                                                     const float* __restrict__ atexts,
                                                     short* __restrict__ Xh,
                                                     short* __restrict__ Xl)
{
    size_t total = (size_t)NTXT * TD;
    for (size_t id = ((size_t)blockIdx.x * 256 + threadIdx.x) * 4; id < total;
         id += (size_t)gridDim.x * 1024) {
        int r = (int)(id / TD);
        int c = (int)(id - (size_t)r * TD);
        const float* s;
        if (r < 64)       s = para + (size_t)r * TD + c;
        else if (r == 64) s = question + c;
        else              s = atexts + (size_t)(r - 65) * TD + c;
        float4 v = *(const float4*)s;
        float vv[4] = {v.x, v.y, v.z, v.w};
#pragma unroll
        for (int e = 0; e < 4; ++e) {
            short h, l; split_rn(vv[e], h, l);
            Xh[id + e] = h; Xl[id + e] = l;
        }
    }
}

// Xp row r = [q + T2[65+r] | btn[r]]  (2048 x 512), 4-wide
__global__ __launch_bounds__(256) void xp_build_split(const short* __restrict__ T2h,
                                                      const short* __restrict__ T2l,
                                                      const short* __restrict__ btnh,
                                                      const short* __restrict__ btnl,
                                                      short* __restrict__ Xh,
                                                      short* __restrict__ Xl)
{
    int idx = blockIdx.x * 256 + threadIdx.x;    // 262144 total
    int r = idx >> 7;
    int c = (idx & 127) << 2;
    s4v h, l;
    if (c < 256) {
        size_t o1 = (size_t)64 * TO + c;
        size_t o2 = (size_t)(65 + r) * TO + c;
        s4v h1 = *(const s4v*)(T2h + o1), l1 = *(const s4v*)(T2l + o1);
        s4v h2 = *(const s4v*)(T2h + o2), l2 = *(const s4v*)(T2l + o2);
#pragma unroll
        for (int e = 0; e < 4; ++e) {
            float v = (bf2f(h1[e]) + bf2f(l1[e])) + (bf2f(h2[e]) + bf2f(l2[e]));
            short hh, ll; split_rn(v, hh, ll);
            h[e] = hh; l[e] = ll;
        }
    } else {
        size_t o = (size_t)r * VO + (c - 256);
        h = *(const s4v*)(btnh + o);
        l = *(const s4v*)(btnl + o);
    }
    size_t out = (size_t)r * 512 + c;
    *(s4v*)(Xh + out) = h;
    *(s4v*)(Xl + out) = l;
}

// GRU gate fusion, 4-wide vectorized
__global__ __launch_bounds__(256) void hn_build(const short* __restrict__ GIh,
                                                const short* __restrict__ GIl,
                                                const short* __restrict__ GHh,
                                                const short* __restrict__ GHl,
                                                const short* __restrict__ ASCh,
                                                const short* __restrict__ ASCl,
                                                short* __restrict__ HNh,
                                                short* __restrict__ HNl)
{
    const int total = NCAND * 128;
    for (int gid = blockIdx.x * 256 + threadIdx.x; gid < total;
         gid += gridDim.x * 256) {
        int r = gid >> 7;
        int c = (gid & 127) << 2;
        int crow, girow;
        if (r < 16) { crow = 0; girow = r; }
        else {
            int rr = r - 16;
            int k  = 1 + (rr >> 8);
            int rem = rr & 255;
            int ci = rem >> 4;
            int aa = rem & 15;
            crow = 1 + (k - 1) * 16 + ci;
            girow = k * 16 + aa;
        }
        size_t gi0 = (size_t)girow * 1536 + c;
        size_t gh0 = (size_t)crow * 1536 + c;
        f32x4 ir = ld4s(GIh, GIl, gi0);
        f32x4 iz = ld4s(GIh, GIl, gi0 + 512);
        f32x4 in = ld4s(GIh, GIl, gi0 + 1024);
        f32x4 hr = ld4s(GHh, GHl, gh0);
        f32x4 hz = ld4s(GHh, GHl, gh0 + 512);
        f32x4 hn = ld4s(GHh, GHl, gh0 + 1024);
        f32x4 h  = ld4s(ASCh, ASCl, (size_t)crow * HH + c);
        s4v oh, ol;
#pragma unroll
        for (int e = 0; e < 4; ++e) {
            float rg = sigm(ir[e] + hr[e]);
            float z  = sigm(iz[e] + hz[e]);
            float n  = tanhf(in[e] + rg * hn[e]);
            float v  = (1.f - z) * n + z * h[e];
            short hh, ll; split_rn(v, hh, ll);
            oh[e] = hh; ol[e] = ll;
        }
        size_t out = (size_t)r * HH + c;
        *(s4v*)(HNh + out) = oh;
        *(s4v*)(HNl + out) = ol;
    }
}

// per-group argmax (first-max), wave per group
__global__ __launch_bounds__(256) void argmax16(const float* __restrict__ LG,
                                                int* __restrict__ idx)
{
    int g = blockIdx.x * 4 + (threadIdx.x >> 6);
    if (g >= NGRP) return;
    int lane = threadIdx.x & 63;
    float v = (lane < 16) ? LG[g * 16 + lane] : -INFINITY;
    int bi = (lane < 16) ? lane : 16;
    for (int off = 8; off >= 1; off >>= 1) {
        float ov = __shfl_xor(v, off);
        int   oi = __shfl_xor(bi, off);
        if (ov > v || (ov == v && oi < bi)) { v = ov; bi = oi; }
    }
    if (lane == 0) idx[g] = bi;
}

// sequential pointer-chase; idx table preloaded to LDS (short dependent chain)
__global__ void chase2(const float* __restrict__ LG, const int* __restrict__ idx,
                       float* __restrict__ out)
{
    __shared__ int sidx[NGRP];
    int lane = threadIdx.x;
    for (int i = lane; i < NGRP; i += 64) sidx[i] = idx[i];
    __syncthreads();
    int g = 0;
    for (int k = 0; k < S_N; ++k) {
        if (lane < 16) out[k * 16 + lane] = LG[g * 16 + lane];
        int ci = sidx[g];
        g = 1 + k * 16 + ci;
    }
}

// ---------------------------------------------------------------------------
extern "C" void kernel_launch(void* const* d_in, const int* in_sizes, int n_in,
                              void* d_out, int out_size, void* d_ws, size_t ws_size,
                              hipStream_t stream)
{
    const float* video      = (const float*)d_in[0];
    const float* para       = (const float*)d_in[1];
    const float* question   = (const float*)d_in[2];
    const float* paras_scr  = (const float*)d_in[3];
    const float* a_texts    = (const float*)d_in[4];
    const float* a_buttons  = (const float*)d_in[5];
    const int*   timestamps = (const int*)d_in[6];
    const float* wv1 = (const float*)d_in[7];
    const float* bv1 = (const float*)d_in[8];
    const float* wv2 = (const float*)d_in[9];
    const float* bv2 = (const float*)d_in[10];
    const float* wt1 = (const float*)d_in[11];
    const float* bt1 = (const float*)d_in[12];
    const float* wt2 = (const float*)d_in[13];
    const float* bt2 = (const float*)d_in[14];
    const float* wp1 = (const float*)d_in[15];
    const float* bp1 = (const float*)d_in[16];
    const float* wp2 = (const float*)d_in[17];
    const float* bp2 = (const float*)d_in[18];
    const float* w_ih = (const float*)d_in[19];
    const float* b_ih = (const float*)d_in[20];
    const float* w_hh = (const float*)d_in[21];
    const float* b_hh = (const float*)d_in[22];
    const float* wj1 = (const float*)d_in[23];
    const float* bj1 = (const float*)d_in[24];
    const float* wj2 = (const float*)d_in[25];
    const float* bj2 = (const float*)d_in[26];
    const float* state0 = (const float*)d_in[27];

    char* wsb = (char*)d_ws;
    size_t off = 0;
    auto alloc = [&](size_t bytes) -> char* {
        size_t o = (off + 255) & ~(size_t)255;
        off = o + bytes;
        return wsb + o;
    };
    auto allocF = [&](size_t n) -> float* { return (float*)alloc(n * 4); };
    auto allocS = [&](size_t n) -> short* { return (short*)alloc(n * 2); };
    auto allocI = [&](size_t n) -> int*   { return (int*)alloc(n * 4); };

    float* sc    = allocF(64);
    float* wtb   = allocF(T_FRAMES);
    float* u     = allocF(VD);
    float* segc  = allocF(512);
    float* bias2 = allocF(1024);
    float* LG    = allocF(NCAND);
    int*   amx   = allocI(NGRP);

    short* Avbh = allocS((size_t)MVB * VD);       // later reused as HNh
    short* Avbl = allocS((size_t)MVB * VD);       // later reused as HNl
    short* H1bh = allocS((size_t)2048 * VD);
    short* H1bl = allocS((size_t)2048 * VD);
    short* Xth  = allocS((size_t)NTXT * TD);
    short* Xtl  = allocS((size_t)NTXT * TD);
    short* T1h  = allocS((size_t)NTXT * TD);
    short* T1l  = allocS((size_t)NTXT * TD);
    short* T2h  = allocS((size_t)NTXT * TO);
    short* T2l  = allocS((size_t)NTXT * TO);
    short* btnh = allocS((size_t)2048 * VO);
    short* btnl = allocS((size_t)2048 * VO);
    short* Xph  = allocS((size_t)2048 * 512);
    short* Xpl  = allocS((size_t)2048 * 512);
    short* P1h  = allocS((size_t)2048 * 1024);
    short* P1l  = allocS((size_t)2048 * 1024);
    short* ASCh = allocS((size_t)NASC * HH);
    short* ASCl = allocS((size_t)NASC * HH);
    short* GIh  = allocS((size_t)2048 * 1536);
    short* GIl  = allocS((size_t)2048 * 1536);
    short* GHh  = allocS((size_t)NASC * 1536);
    short* GHl  = allocS((size_t)NASC * 1536);
    short* IPh  = ASCh + HH;                      // IP = ASC rows 1..2048
    short* IPl  = ASCl + HH;
    short* HNh  = Avbh;                           // Avb dead after G1
    short* HNl  = Avbl;

    short* wv1Th = allocS((size_t)VD * VD);     short* wv1Tl = allocS((size_t)VD * VD);
    short* wt1Th = allocS((size_t)TD * TD);     short* wt1Tl = allocS((size_t)TD * TD);
    short* wt2Th = allocS((size_t)TO * TD);     short* wt2Tl = allocS((size_t)TO * TD);
    short* wv2Th = allocS((size_t)VO * VD);     short* wv2Tl = allocS((size_t)VO * VD);
    short* wp1Th = allocS((size_t)1024 * 1024); short* wp1Tl = allocS((size_t)1024 * 1024);
    short* wp2Th = allocS((size_t)HH * 1024);   short* wp2Tl = allocS((size_t)HH * 1024);
    short* wj1Th = allocS((size_t)HH * HH);     short* wj1Tl = allocS((size_t)HH * HH);
    short* wihSh = allocS((size_t)1536 * HH);   short* wihSl = allocS((size_t)1536 * HH);
    short* whhSh = allocS((size_t)1536 * HH);   short* whhSl = allocS((size_t)1536 * HH);

    GD gE; gE.Ah = gE.Al = gE.Bh = gE.Bl = nullptr; gE.bias = nullptr;
    gE.Ch = gE.Cl = nullptr; gE.M = gE.N = gE.K = gE.lda = gE.ldb = 0;
    gE.gx = 1; gE.nblk = 0; gE.mode = 0;

    // 1. prolog
    prolog<<<131, 256, 0, stream>>>(paras_scr, sc, u, state0, ASCh, ASCl, bj2, LG);
    // 2. frame weights
    wt_kernel<<<T_FRAMES / 256, 256, 0, stream>>>(timestamps, sc, wtb);
    // 3. weight splits (wp1 transposed in FULL: [0:512) rows feed bias2k,
    //    [512:1024) feed G5 via ldb=1024 column offset)
    {
        PrepArgs pa;
        const float* s[9] = {wv1, wt1, wt2, wv2, wp1, wp2, wj1, w_ih, w_hh};
        short* dh[9] = {wv1Th, wt1Th, wt2Th, wv2Th, wp1Th, wp2Th, wj1Th, wihSh, whhSh};
        short* dl[9] = {wv1Tl, wt1Tl, wt2Tl, wv2Tl, wp1Tl, wp2Tl, wj1Tl, wihSl, whhSl};
        int K[9] = {VD, TD, TD, VD, 1024, 1024, HH, HH, HH};
        int N[9] = {VD, TD, TO, VO, 1024, HH, HH, 1536, 1536};
        int tr[9] = {1, 1, 1, 1, 1, 1, 1, 0, 0};
        for (int i = 0; i < 9; ++i) {
            pa.src[i] = s[i]; pa.dh[i] = dh[i]; pa.dl[i] = dl[i];
            pa.K[i] = K[i]; pa.N[i] = N[i]; pa.tr[i] = tr[i];
        }
        prep_weights<<<dim3(1024, 9), 256, 0, stream>>>(pa);
    }
    // 4-5. activation splits
    asplit_vb<<<4608, 256, 0, stream>>>(video, a_buttons, Avbh, Avbl);
    copy_xt_split<<<1586, 256, 0, stream>>>(para, question, a_texts, Xth, Xtl);

    // L-A [SB32]: {G1 (video+buttons layer-1, fused u-reduce), G3 (text layer-1)}
    {
        GD g1{Avbh, Avbl, wv1Th, wv1Tl, bv1, H1bh, H1bl, MVB, VD, VD, VD, VD, 8, 1152, 2};
        GD g3{Xth, Xtl, wt1Th, wt1Tl, bt1, T1h, T1l, NTXT, TD, TD, TD, TD, 6, 102, 1};
        gemmk<32><<<1254, 256, 0, stream>>>(g1, g3, wtb, u, nullptr, nullptr);
    }
    // L-B [DB64]: {G2 (btn), G4 (text layer-2)}
    {
        GD g2{H1bh, H1bl, wv2Th, wv2Tl, bv2, btnh, btnl, 2048, VO, VD, VD, VD, 2, 32, 0};
        GD g4{T1h, T1l, wt2Th, wt2Tl, bt2, T2h, T2l, NTXT, TO, TD, TD, TD, 2, 34, 0};
        gemmk<64><<<66, 512, 0, stream>>>(g2, g4, nullptr, nullptr, nullptr, nullptr);
    }
    // segment vectors + folded bias2 (wave-parallel)
    mkseg<<<65, 256, 0, stream>>>(u, wv2Th, wv2Tl, bv2, sc, T2h, T2l, segc);
    bias2k<<<256, 256, 0, stream>>>(segc, wp1Th, wp1Tl, bp1, bias2);
    // Xp = [qa | btn]
    xp_build_split<<<1024, 256, 0, stream>>>(T2h, T2l, btnh, btnl, Xph, Xpl);
    // G5/G6 [DB64]: pre-GRU MLP (G5 K=512 via bias2 fold; B = wp1T cols [512:))
    {
        GD g5{Xph, Xpl, wp1Th + 512, wp1Tl + 512, bias2, P1h, P1l,
              2048, 1024, 512, 512, 1024, 8, 128, 1};
        gemmk<64><<<128, 512, 0, stream>>>(g5, gE, nullptr, nullptr, nullptr, nullptr);
    }
    {
        GD g6{P1h, P1l, wp2Th, wp2Tl, bp2, IPh, IPl, 2048, HH, 1024, 1024, 1024, 4, 64, 0};
        gemmk<64><<<64, 512, 0, stream>>>(g6, gE, nullptr, nullptr, nullptr, nullptr);
    }
    // L-C [DB64]: {G7, G8} GRU gate GEMMs
    {
        GD g7{IPh, IPl, wihSh, wihSl, b_ih, GIh, GIl, 2048, 1536, HH, HH, HH, 12, 192, 0};
        GD g8{ASCh, ASCl, whhSh, whhSl, b_hh, GHh, GHl, NASC, 1536, HH, HH, HH, 12, 204, 0};
        gemmk<64><<<396, 512, 0, stream>>>(g7, g8, nullptr, nullptr, nullptr, nullptr);
    }
    // gate fusion
    hn_build<<<4096, 256, 0, stream>>>(GIh, GIl, GHh, GHl, ASCh, ASCl, HNh, HNl);
    // G9 [DB64 mode3]: judge MLP fused to logits
    {
        GD g9{HNh, HNl, wj1Th, wj1Tl, bj1, nullptr, nullptr, NCAND, HH, HH, HH, HH, 4, 1020, 3};
        gemmk<64><<<1020, 512, 0, stream>>>(g9, gE, nullptr, nullptr, wj2, LG);
    }
    // parallel argmax + LDS-table chase
    argmax16<<<(NGRP + 3) / 4, 256, 0, stream>>>(LG, amx);
    chase2<<<1, 64, 0, stream>>>(LG, amx, (float*)d_out);
}